// Round 13
// baseline (1323.488 us; speedup 1.0000x reference)
//
#include <hip/hip_runtime.h>
#include <hip/hip_bf16.h>
#include <cstdint>
#include <cstddef>

#define BB 2
#define TT 2048
#define DD 2048
#define NH 16
#define NKV 4
#define HD 128
#define NI 8192
#define MM (BB*TT)

typedef __bf16 bf16x8 __attribute__((ext_vector_type(8)));
typedef float  f32x4  __attribute__((ext_vector_type(4)));

__device__ __forceinline__ void gload_lds16(const void* g, void* l) {
  __builtin_amdgcn_global_load_lds((__attribute__((address_space(1))) void*)g,
                                   (__attribute__((address_space(3))) void*)l,
                                   16, 0, 0);
}

// bijective XCD swizzle (m204)
__device__ __forceinline__ int xcd_swizzle(int wg, int nwg) {
  int xcd = wg & 7;
  int l = wg >> 3;
  int q = nwg >> 3, r = nwg & 7;
  return (xcd < r ? xcd * (q + 1) : r * (q + 1) + (xcd - r) * q) + l;
}

// ---------------- RoPE tables ----------------
__global__ __launch_bounds__(128) void rope_tables_k(float* __restrict__ cosT,
                                                     float* __restrict__ sinT) {
  int pos = blockIdx.x;
  int d = threadIdx.x;
  int f = d & 63;
  float inv = powf(10000.0f, -((float)(2 * f)) / 128.0f);
  float ang = inv * (float)pos;
  cosT[pos * 128 + d] = cosf(ang);
  sinT[pos * 128 + d] = sinf(ang);
}

// ---------------- transpose + convert to bf16 ----------------
template <typename TIN>
__global__ __launch_bounds__(256) void transpose_to_bf16_k(const TIN* __restrict__ in,
                                                           __bf16* __restrict__ out,
                                                           int R, int C) {
  __shared__ float t[32][33];
  int c0 = blockIdx.x * 32, r0 = blockIdx.y * 32;
  int tx = threadIdx.x & 31;
  int ty = threadIdx.x >> 5;
#pragma unroll
  for (int i = 0; i < 4; i++) {
    int r = ty + i * 8;
    t[r][tx] = (float)in[(size_t)(r0 + r) * C + c0 + tx];
  }
  __syncthreads();
#pragma unroll
  for (int i = 0; i < 4; i++) {
    int r = ty + i * 8;
    out[(size_t)(c0 + r) * R + r0 + tx] = (__bf16)t[tx][r];
  }
}

// ---------------- RMSNorm ----------------
__global__ __launch_bounds__(256) void rmsnorm_k(const float* __restrict__ x,
                                                 const float* __restrict__ w,
                                                 __bf16* __restrict__ out) {
  int row = blockIdx.x;
  const float* xr = x + (size_t)row * DD;
  int t = threadIdx.x;
  float4 a = ((const float4*)xr)[2 * t];
  float4 b = ((const float4*)xr)[2 * t + 1];
  float ss = a.x * a.x + a.y * a.y + a.z * a.z + a.w * a.w +
             b.x * b.x + b.y * b.y + b.z * b.z + b.w * b.w;
#pragma unroll
  for (int off = 32; off; off >>= 1) ss += __shfl_xor(ss, off, 64);
  __shared__ float red[4];
  if ((t & 63) == 0) red[t >> 6] = ss;
  __syncthreads();
  float tot = red[0] + red[1] + red[2] + red[3];
  float rs = rsqrtf(tot * (1.0f / DD) + 1e-6f);
  const float4 w1 = ((const float4*)w)[2 * t];
  const float4 w2 = ((const float4*)w)[2 * t + 1];
  bf16x8 ov;
  ov[0] = (__bf16)(a.x * rs * w1.x);
  ov[1] = (__bf16)(a.y * rs * w1.y);
  ov[2] = (__bf16)(a.z * rs * w1.z);
  ov[3] = (__bf16)(a.w * rs * w1.w);
  ov[4] = (__bf16)(b.x * rs * w2.x);
  ov[5] = (__bf16)(b.y * rs * w2.y);
  ov[6] = (__bf16)(b.z * rs * w2.z);
  ov[7] = (__bf16)(b.w * rs * w2.w);
  *(bf16x8*)(out + (size_t)row * DD + t * 8) = ov;
}

enum { G_QG = 0, G_RES = 1, G_SILU = 2, G_PART = 3 };

// ---------------- shared epilogue ----------------
template <int EPI>
__device__ __forceinline__ void gemm_epilogue(
    f32x4 (&acc)[8][4], int m0, int n0, int wr, int wc, int fr, int fg, int kz,
    __bf16* outB, float* outF, __bf16* outQ, __bf16* outG,
    const float* bias, const float* residual, const float* cosT, const float* sinT,
    const int* posids, int N, float oscale) {
#pragma unroll
  for (int mi = 0; mi < 8; mi++) {
    const int row = m0 + wr * 128 + mi * 16 + fg * 4;
#pragma unroll
    for (int ni = 0; ni < 4; ni++) {
      const int col = n0 + wc * 64 + ni * 16 + fr;
#pragma unroll
      for (int j = 0; j < 4; j++) {
        float v = acc[mi][ni][j];
        const int r = row + j;
        if constexpr (EPI == G_QG) {
          float vp = __shfl_xor(v, 1, 64);
          if (n0 < 2048) {
            int pos = posids[r];
            int d = col & 127;
            float c = cosT[pos * 128 + d], sn2 = sinT[pos * 128 + d];
            float o = (col & 1) ? (v * c + vp * sn2) : (v * c - vp * sn2);
            outQ[(size_t)r * 2048 + col] = (__bf16)(o * oscale);
          } else {
            float xx = v + bias[col - 2048];
            outG[(size_t)r * 2048 + (col - 2048)] = (__bf16)(1.0f / (1.0f + expf(-xx)));
          }
        } else if constexpr (EPI == G_RES) {
          outF[(size_t)r * N + col] = v + residual[(size_t)r * N + col];
        } else if constexpr (EPI == G_SILU) {
          outB[(size_t)r * N + col] = (__bf16)(v / (1.0f + expf(-v)));
        } else {
          outB[(size_t)(kz * MM + r) * N + col] = (__bf16)v;
        }
      }
    }
  }
}

// ---------------- GEMM 256x256, BK=32, 3-buffer ring, 2 phases (r11 champion) ----------------
template <int EPI>
__global__ __launch_bounds__(512) void gemm256_k(
    const __bf16* __restrict__ A, const __bf16* __restrict__ Bt,
    __bf16* __restrict__ outB, float* __restrict__ outF,
    __bf16* __restrict__ outQ, __bf16* __restrict__ outG,
    const float* __restrict__ bias, const float* __restrict__ residual,
    const float* __restrict__ cosT, const float* __restrict__ sinT,
    const int* __restrict__ posids, int N, int K, int ldk, float oscale) {
  __shared__ __align__(16) __bf16 Ab[3][256 * 32];
  __shared__ __align__(16) __bf16 Bb[3][256 * 32];
  const int tid = threadIdx.x;
  const int lane = tid & 63;
  const int wid = tid >> 6;
  const int wr = wid >> 2;
  const int wc = wid & 3;
  const int fr = lane & 15;
  const int fg = lane >> 4;

  const int nwg = gridDim.x * gridDim.y;
  int wg = xcd_swizzle(blockIdx.y * gridDim.x + blockIdx.x, nwg);
  const int bx = wg % gridDim.x, by = wg / gridDim.x;
  const int m0 = by * 256;
  const int n0 = bx * 256;
  const int kz = blockIdx.z;
  const int kBase = kz * K;

  const int srow0 = wid * 32 + (lane >> 2);
  const int scol = (((lane & 3) ^ ((lane >> 3) & 3)) << 3);
  const __bf16* aS0 = A + (size_t)(m0 + srow0) * ldk + kBase + scol;
  const __bf16* aS1 = aS0 + (size_t)16 * ldk;
  const __bf16* bS0 = Bt + (size_t)(n0 + srow0) * ldk + kBase + scol;
  const __bf16* bS1 = bS0 + (size_t)16 * ldk;
  const int e0 = (wid * 2) * 512;
  const int e1 = (wid * 2 + 1) * 512;

  const int nt = K / 32;

#define STAGE_A(kt, s)                          \
  {                                             \
    const int k0_ = (kt) * 32;                  \
    gload_lds16(aS0 + k0_, &Ab[(s)][e0]);       \
    gload_lds16(aS1 + k0_, &Ab[(s)][e1]);       \
  }
#define STAGE_B(kt, s)                          \
  {                                             \
    const int k0_ = (kt) * 32;                  \
    gload_lds16(bS0 + k0_, &Bb[(s)][e0]);       \
    gload_lds16(bS1 + k0_, &Bb[(s)][e1]);       \
  }

  STAGE_A(0, 0);
  STAGE_B(0, 0);
  STAGE_A(1, 1);
  STAGE_B(1, 1);
  asm volatile("s_waitcnt vmcnt(4)" ::: "memory");
  __builtin_amdgcn_s_barrier();

  f32x4 acc[8][4];
#pragma unroll
  for (int i = 0; i < 8; i++)
#pragma unroll
    for (int j = 0; j < 4; j++) acc[i][j] = (f32x4){0.f, 0.f, 0.f, 0.f};

  const int asl = (fg ^ ((fr >> 1) & 3)) * 8;

  for (int t = 0; t < nt; ++t) {
    const int s = t % 3;
    const int sn = (t + 2) % 3;
    bf16x8 af[4], bfr[4];
#pragma unroll
    for (int mi = 0; mi < 4; mi++)
      af[mi] = *(const bf16x8*)&Ab[s][(wr * 128 + mi * 16 + fr) * 32 + asl];
#pragma unroll
    for (int ni = 0; ni < 4; ni++)
      bfr[ni] = *(const bf16x8*)&Bb[s][(wc * 64 + ni * 16 + fr) * 32 + asl];
    if (t + 2 < nt) STAGE_A(t + 2, sn);
    __builtin_amdgcn_s_barrier();
    asm volatile("s_waitcnt lgkmcnt(0)" ::: "memory");
    __builtin_amdgcn_sched_barrier(0);
    __builtin_amdgcn_s_setprio(1);
#pragma unroll
    for (int mi = 0; mi < 4; mi++)
#pragma unroll
      for (int ni = 0; ni < 4; ni++)
        acc[mi][ni] =
            __builtin_amdgcn_mfma_f32_16x16x32_bf16(af[mi], bfr[ni], acc[mi][ni], 0, 0, 0);
    __builtin_amdgcn_s_setprio(0);
    __builtin_amdgcn_s_barrier();
    bf16x8 af2[4];
#pragma unroll
    for (int mi = 0; mi < 4; mi++)
      af2[mi] = *(const bf16x8*)&Ab[s][(wr * 128 + (mi + 4) * 16 + fr) * 32 + asl];
    if (t + 2 < nt) STAGE_B(t + 2, sn);
    __builtin_amdgcn_s_barrier();
    asm volatile("s_waitcnt lgkmcnt(0)" ::: "memory");
    __builtin_amdgcn_sched_barrier(0);
    __builtin_amdgcn_s_setprio(1);
#pragma unroll
    for (int mi = 0; mi < 4; mi++)
#pragma unroll
      for (int ni = 0; ni < 4; ni++)
        acc[mi + 4][ni] =
            __builtin_amdgcn_mfma_f32_16x16x32_bf16(af2[mi], bfr[ni], acc[mi + 4][ni], 0, 0, 0);
    __builtin_amdgcn_s_setprio(0);
    if (t + 2 < nt) {
      asm volatile("s_waitcnt vmcnt(4)" ::: "memory");
    } else {
      asm volatile("s_waitcnt vmcnt(0)" ::: "memory");
    }
    __builtin_amdgcn_s_barrier();
  }
#undef STAGE_A
#undef STAGE_B

  gemm_epilogue<EPI>(acc, m0, n0, wr, wc, fr, fg, kz, outB, outF, outQ, outG, bias,
                     residual, cosT, sinT, posids, N, oscale);
}

// ---------------- GEMM 256x256, BK=64, 4x16-MFMA phases, v3 low-VGPR (single a[], b0 re-read) ----
template <int EPI>
__global__ __launch_bounds__(512, 1) void gemm256x64_k(
    const __bf16* __restrict__ A, const __bf16* __restrict__ Bt,
    __bf16* __restrict__ outB, float* __restrict__ outF,
    __bf16* __restrict__ outQ, __bf16* __restrict__ outG,
    const float* __restrict__ bias, const float* __restrict__ residual,
    const float* __restrict__ cosT, const float* __restrict__ sinT,
    const int* __restrict__ posids, int N, int K, int ldk, float oscale) {
  __shared__ __align__(16) __bf16 Ab[2][256 * 64];
  __shared__ __align__(16) __bf16 Bb[2][256 * 64];
  const int tid = threadIdx.x;
  const int lane = tid & 63;
  const int wid = tid >> 6;
  const int wr = wid >> 2;
  const int wc = wid & 3;
  const int fr = lane & 15;
  const int fg = lane >> 4;

  const int nwg = gridDim.x * gridDim.y;
  int wg = xcd_swizzle(blockIdx.y * gridDim.x + blockIdx.x, nwg);
  const int bx = wg % gridDim.x, by = wg / gridDim.x;
  const int m0 = by * 256;
  const int n0 = bx * 256;
  const int kz = blockIdx.z;
  const int kBase = kz * K;

  const int rofs = lane >> 3;
  const int swz = ((lane & 7) ^ rofs) * 8;
  const int gA0 = ((wid & 4) << 5) + ((wid & 3) << 4);
  const int gB0 = ((wid >> 1) << 6) + ((wid & 1) << 4);
  const __bf16* aSrcB = A + (size_t)(m0 + rofs) * ldk + kBase + swz;
  const __bf16* bSrcB = Bt + (size_t)(n0 + rofs) * ldk + kBase + swz;

  const int nt = K / 64;

#define STGA64(buf, h, T)                                                            \
  {                                                                                  \
    const int g0_ = gA0 + (h) * 64;                                                  \
    gload_lds16(aSrcB + (size_t)g0_ * ldk + (size_t)(T) * 64, &Ab[buf][g0_ * 64]);   \
    gload_lds16(aSrcB + (size_t)(g0_ + 8) * ldk + (size_t)(T) * 64,                  \
                &Ab[buf][(g0_ + 8) * 64]);                                           \
  }
#define STGB64(buf, h, T)                                                            \
  {                                                                                  \
    const int g0_ = gB0 + (h) * 32;                                                  \
    gload_lds16(bSrcB + (size_t)g0_ * ldk + (size_t)(T) * 64, &Bb[buf][g0_ * 64]);   \
    gload_lds16(bSrcB + (size_t)(g0_ + 8) * ldk + (size_t)(T) * 64,                  \
                &Bb[buf][(g0_ + 8) * 64]);                                           \
  }
#define RD64_A(dst, buf, mh)                                                           \
  _Pragma("unroll") for (int mt = 0; mt < 4; mt++)                                     \
  _Pragma("unroll") for (int kk = 0; kk < 2; kk++)                                     \
      dst[mt][kk] = *(const bf16x8*)&Ab[buf][(wr * 128 + (mh) * 64 + mt * 16 + fr) * 64 + \
                                             (((kk * 4 + fg) ^ (fr & 7)) << 3)];
#define RD64_B(dst, buf, nh)                                                           \
  _Pragma("unroll") for (int nt2 = 0; nt2 < 2; nt2++)                                  \
  _Pragma("unroll") for (int kk = 0; kk < 2; kk++)                                     \
      dst[nt2][kk] = *(const bf16x8*)&Bb[buf][(wc * 64 + (nh) * 32 + nt2 * 16 + fr) * 64 + \
                                              (((kk * 4 + fg) ^ (fr & 7)) << 3)];
#define MFMA64(a, b, MH, NHh)                                                          \
  _Pragma("unroll") for (int mt = 0; mt < 4; mt++)                                     \
  _Pragma("unroll") for (int nt2 = 0; nt2 < 2; nt2++)                                  \
  _Pragma("unroll") for (int kk = 0; kk < 2; kk++)                                     \
      acc[(MH) * 4 + mt][(NHh) * 2 + nt2] = __builtin_amdgcn_mfma_f32_16x16x32_bf16(   \
          a[mt][kk], b[nt2][kk], acc[(MH) * 4 + mt][(NHh) * 2 + nt2], 0, 0, 0);
#define PH_SYNC                                           \
  __builtin_amdgcn_s_barrier();                           \
  asm volatile("s_waitcnt lgkmcnt(0)" ::: "memory");      \
  __builtin_amdgcn_sched_barrier(0);                      \
  __builtin_amdgcn_s_setprio(1);
#define PH_END                                            \
  __builtin_amdgcn_s_setprio(0);                          \
  __builtin_amdgcn_s_barrier();

  // TILE v3: live fragments minimized — ONE a[4][2] (overwritten at ph3) + b0 + b1 = 64 VGPR.
  // Quadrant order (0,0)->(0,1)->(1,1)->(1,0); b0 re-read from LDS at ph4 (region not
  // overwritten until tile T+1 ph1, behind two barriers -> safe; staging chain as r8 = verified).
#define TILE64(T, CUR, OTH, S0, S123, VMSTR)              \
  {                                                       \
    bf16x8 a[4][2], b0[2][2], b1[2][2];                   \
    RD64_A(a, CUR, 0);                                    \
    RD64_B(b0, CUR, 0);                                   \
    if (S0) STGB64(OTH, 0, (T) + 1);                      \
    PH_SYNC;                                              \
    MFMA64(a, b0, 0, 0);                                  \
    PH_END;                                               \
    RD64_B(b1, CUR, 1);                                   \
    if (S123) STGA64(CUR, 0, (T) + 2);                    \
    PH_SYNC;                                              \
    MFMA64(a, b1, 0, 1);                                  \
    PH_END;                                               \
    RD64_A(a, CUR, 1);                                    \
    if (S123) STGB64(CUR, 1, (T) + 2);                    \
    PH_SYNC;                                              \
    MFMA64(a, b1, 1, 1);                                  \
    PH_END;                                               \
    RD64_B(b0, CUR, 0);                                   \
    if (S123) STGA64(CUR, 1, (T) + 2);                    \
    __builtin_amdgcn_s_barrier();                         \
    asm volatile("s_waitcnt lgkmcnt(0)" ::: "memory");    \
    __builtin_amdgcn_sched_barrier(0);                    \
    __builtin_amdgcn_s_setprio(1);                        \
    MFMA64(a, b0, 1, 0);                                  \
    __builtin_amdgcn_s_setprio(0);                        \
    asm volatile("s_waitcnt " VMSTR ::: "memory");        \
    __builtin_amdgcn_s_barrier();                         \
  }

  f32x4 acc[8][4];
#pragma unroll
  for (int i = 0; i < 8; i++)
#pragma unroll
    for (int j = 0; j < 4; j++) acc[i][j] = (f32x4){0.f, 0.f, 0.f, 0.f};

  STGB64(0, 0, 0); STGA64(0, 0, 0); STGB64(0, 1, 0); STGA64(0, 1, 0);
  STGA64(1, 0, 1); STGB64(1, 1, 1); STGA64(1, 1, 1);
  asm volatile("s_waitcnt vmcnt(6)" ::: "memory");
  __builtin_amdgcn_s_barrier();

  for (int t = 0; t < nt; t += 2) {
    if (t + 2 < nt) {
      TILE64(t, 0, 1, true, true, "vmcnt(6)");
      TILE64(t + 1, 1, 0, true, true, "vmcnt(6)");
    } else {
      TILE64(t, 0, 1, true, false, "vmcnt(0)");
      TILE64(t + 1, 1, 0, false, false, "vmcnt(0)");
    }
  }
#undef TILE64
#undef PH_SYNC
#undef PH_END
#undef MFMA64
#undef RD64_A
#undef RD64_B
#undef STGA64
#undef STGB64

  gemm_epilogue<EPI>(acc, m0, n0, wr, wc, fr, fg, kz, outB, outF, outQ, outG, bias,
                     residual, cosT, sinT, posids, N, oscale);
}

// ---------------- combine: out = part0 + part1 + res (f32) ----------------
__global__ __launch_bounds__(256) void combine_k(const __bf16* __restrict__ parts,
                                                 const float* __restrict__ res,
                                                 float* __restrict__ out) {
  size_t i = ((size_t)blockIdx.x * 256 + threadIdx.x) * 8;
  bf16x8 p0 = *(const bf16x8*)&parts[i];
  bf16x8 p1 = *(const bf16x8*)&parts[(size_t)MM * 2048 + i];
  float4 a = *(const float4*)&res[i];
  float4 b = *(const float4*)&res[i + 4];
  float4 o0, o1;
  o0.x = (float)p0[0] + (float)p1[0] + a.x;
  o0.y = (float)p0[1] + (float)p1[1] + a.y;
  o0.z = (float)p0[2] + (float)p1[2] + a.z;
  o0.w = (float)p0[3] + (float)p1[3] + a.w;
  o1.x = (float)p0[4] + (float)p1[4] + b.x;
  o1.y = (float)p0[5] + (float)p1[5] + b.y;
  o1.z = (float)p0[6] + (float)p1[6] + b.z;
  o1.w = (float)p0[7] + (float)p1[7] + b.w;
  *(float4*)&out[i] = o0;
  *(float4*)&out[i + 4] = o1;
}

// ---------------- fused combine + RMSNorm ----------------
__global__ __launch_bounds__(256) void combine_rms_k(const __bf16* __restrict__ parts,
                                                     const float* __restrict__ res,
                                                     const float* __restrict__ w,
                                                     float* __restrict__ h1,
                                                     __bf16* __restrict__ h2) {
  const int row = blockIdx.x;
  const int t = threadIdx.x;
  const size_t i = (size_t)row * 2048 + t * 8;
  bf16x8 p0 = *(const bf16x8*)&parts[i];
  bf16x8 p1 = *(const bf16x8*)&parts[(size_t)MM * 2048 + i];
  float4 a = *(const float4*)&res[i];
  float4 b = *(const float4*)&res[i + 4];
  float v[8];
  v[0] = (float)p0[0] + (float)p1[0] + a.x;
  v[1] = (float)p0[1] + (float)p1[1] + a.y;
  v[2] = (float)p0[2] + (float)p1[2] + a.z;
  v[3] = (float)p0[3] + (float)p1[3] + a.w;
  v[4] = (float)p0[4] + (float)p1[4] + b.x;
  v[5] = (float)p0[5] + (float)p1[5] + b.y;
  v[6] = (float)p0[6] + (float)p1[6] + b.z;
  v[7] = (float)p0[7] + (float)p1[7] + b.w;
  float4 o0 = {v[0], v[1], v[2], v[3]};
  float4 o1 = {v[4], v[5], v[6], v[7]};
  *(float4*)&h1[i] = o0;
  *(float4*)&h1[i + 4] = o1;
  float ss = 0.f;
#pragma unroll
  for (int k = 0; k < 8; k++) ss += v[k] * v[k];
#pragma unroll
  for (int off = 32; off; off >>= 1) ss += __shfl_xor(ss, off, 64);
  __shared__ float red[4];
  if ((t & 63) == 0) red[t >> 6] = ss;
  __syncthreads();
  float tot = red[0] + red[1] + red[2] + red[3];
  float rs = rsqrtf(tot * (1.0f / DD) + 1e-6f);
  const float4 w1 = ((const float4*)w)[2 * t];
  const float4 w2 = ((const float4*)w)[2 * t + 1];
  bf16x8 ov;
  ov[0] = (__bf16)(v[0] * rs * w1.x);
  ov[1] = (__bf16)(v[1] * rs * w1.y);
  ov[2] = (__bf16)(v[2] * rs * w1.z);
  ov[3] = (__bf16)(v[3] * rs * w1.w);
  ov[4] = (__bf16)(v[4] * rs * w2.x);
  ov[5] = (__bf16)(v[5] * rs * w2.y);
  ov[6] = (__bf16)(v[6] * rs * w2.z);
  ov[7] = (__bf16)(v[7] * rs * w2.w);
  *(bf16x8*)(h2 + i) = ov;
}

// ---------------- K+V fused projection (128x128 tile) ----------------
__global__ __launch_bounds__(256) void gemm_kv_k(
    const __bf16* __restrict__ A, const __bf16* __restrict__ Bt,
    __bf16* __restrict__ kOut, __bf16* __restrict__ vOut,
    const float* __restrict__ cosT, const float* __restrict__ sinT,
    const int* __restrict__ posids, int K) {
  __shared__ __align__(16) __bf16 As[128 * 32];
  __shared__ __align__(16) __bf16 Bs[128 * 32];
  const int tid = threadIdx.x;
  const int lane = tid & 63;
  const int w = tid >> 6;
  const int wm = w >> 1, wn = w & 1;

  const int nwg = gridDim.x * gridDim.y;
  int wg = xcd_swizzle(blockIdx.y * gridDim.x + blockIdx.x, nwg);
  const int bx = wg % gridDim.x, by = wg / gridDim.x;
  const int m0 = by * 128;
  const int n0 = bx * 128;

  const int lr = lane >> 2;
  const int lc = (lane & 3) * 8;
  const __bf16* aSrc = A + (size_t)(m0 + 32 * w + lr) * K + lc;
  const __bf16* bSrc = Bt + (size_t)(n0 + 32 * w + lr) * K + lc;
  __bf16* aDst = &As[w * 1024];
  __bf16* bDst = &Bs[w * 1024];

  f32x4 acc[4][4];
#pragma unroll
  for (int i = 0; i < 4; i++)
#pragma unroll
    for (int j = 0; j < 4; j++) acc[i][j] = (f32x4){0.f, 0.f, 0.f, 0.f};

  const int fr = lane & 15;
  const int fc = (lane >> 4) * 8;

  for (int k0 = 0; k0 < K; k0 += 32) {
    __syncthreads();
    gload_lds16(aSrc + k0, aDst);
    gload_lds16(aSrc + k0 + (size_t)16 * K, aDst + 512);
    gload_lds16(bSrc + k0, bDst);
    gload_lds16(bSrc + k0 + (size_t)16 * K, bDst + 512);
    asm volatile("s_waitcnt vmcnt(0)" ::: "memory");
    __syncthreads();

    bf16x8 af[4], bfg[4];
#pragma unroll
    for (int i = 0; i < 4; i++)
      af[i] = *(const bf16x8*)&As[(wm * 64 + i * 16 + fr) * 32 + fc];
#pragma unroll
    for (int i = 0; i < 4; i++)
      bfg[i] = *(const bf16x8*)&Bs[(wn * 64 + i * 16 + fr) * 32 + fc];
#pragma unroll
    for (int mi = 0; mi < 4; mi++)
#pragma unroll
      for (int ni = 0; ni < 4; ni++)
        acc[mi][ni] =
            __builtin_amdgcn_mfma_f32_16x16x32_bf16(af[mi], bfg[ni], acc[mi][ni], 0, 0, 0);
  }

  const int fg = lane >> 4;
#pragma unroll
  for (int mi = 0; mi < 4; mi++) {
#pragma unroll
    for (int ni = 0; ni < 4; ni++) {
#pragma unroll
      for (int j = 0; j < 4; j++) {
        int row = m0 + wm * 64 + mi * 16 + fg * 4 + j;
        int col = n0 + wn * 64 + ni * 16 + fr;
        float v = acc[mi][ni][j];
        float vp = __shfl_xor(v, 1, 64);
        if (col < 512) {
          int pos = posids[row];
          int d = col & 127;
          float c = cosT[pos * 128 + d];
          float s = sinT[pos * 128 + d];
          float o = (col & 1) ? (v * c + vp * s) : (v * c - vp * s);
          kOut[(size_t)row * 512 + col] = (__bf16)o;
        } else {
          vOut[(size_t)row * 512 + (col - 512)] = (__bf16)v;
        }
      }
    }
  }
}

// ---------------- Flash attention (r3, verified) ----------------
__global__ __launch_bounds__(256) void attn_k(const __bf16* __restrict__ Q,
                                              const __bf16* __restrict__ Kb,
                                              const __bf16* __restrict__ Vt,
                                              const __bf16* __restrict__ Gate,
                                              __bf16* __restrict__ Out) {
  __shared__ __align__(16) __bf16 Ks[2][64 * 128];
  __shared__ __align__(16) __bf16 Vs[2][128 * 64];
  __shared__ __align__(16) __bf16 Ps[4][16 * 64];
  const int tid = threadIdx.x;
  const int lane = tid & 63;
  const int w = tid >> 6;
  const int fr = lane & 15;
  const int fg = lane >> 4;

  const int nwg = gridDim.x * gridDim.y;
  int wg = xcd_swizzle(blockIdx.y * gridDim.x + blockIdx.x, nwg);
  const int qb = wg % gridDim.x;
  const int bh = wg / gridDim.x;
  const int q0 = qb * 64;
  const int b = bh >> 4, h = bh & 15;
  const int g = h >> 2;

  const size_t qrow = (size_t)(b * TT + q0 + w * 16 + fr);
  bf16x8 qf[4];
#pragma unroll
  for (int kt = 0; kt < 4; kt++)
    qf[kt] = *(const bf16x8*)&Q[qrow * 2048 + h * 128 + kt * 32 + fg * 8];

  const __bf16* kPtr[4];
  const __bf16* vPtr[4];
#pragma unroll
  for (int i = 0; i < 4; i++) {
    int krow = w * 16 + i * 4 + (lane >> 4);
    int kcol8 = (lane & 15) ^ (krow & 15);
    kPtr[i] = Kb + (size_t)(b * TT + krow) * 512 + g * 128 + kcol8 * 8;
    int dloc = w * 32 + i * 8 + (lane >> 3);
    int kv8 = (lane & 7) ^ (dloc & 7);
    vPtr[i] = Vt + (size_t)(g * 128 + dloc) * (size_t)MM + b * TT + kv8 * 8;
  }

  f32x4 o[8];
#pragma unroll
  for (int i = 0; i < 8; i++) o[i] = (f32x4){0.f, 0.f, 0.f, 0.f};
  float mrow[4] = {-3e38f, -3e38f, -3e38f, -3e38f};
  float lrow[4] = {0.f, 0.f, 0.f, 0.f};

  const int nsteps = qb + 1;

#pragma unroll
  for (int i = 0; i < 4; i++) {
    gload_lds16(kPtr[i], &Ks[0][w * 2048 + i * 512]);
    gload_lds16(vPtr[i], &Vs[0][w * 2048 + i * 512]);
  }
  __syncthreads();

  for (int t = 0; t < nsteps; t++) {
    const int cur = t & 1;
    const int kb = t * 64;
    if (t + 1 < nsteps) {
      const int nb = kb + 64;
#pragma unroll
      for (int i = 0; i < 4; i++) {
        gload_lds16(kPtr[i] + (size_t)nb * 512, &Ks[cur ^ 1][w * 2048 + i * 512]);
        gload_lds16(vPtr[i] + nb, &Vs[cur ^ 1][w * 2048 + i * 512]);
      }
    }

    f32x4 s[4];
#pragma unroll
    for (int nc = 0; nc < 4; nc++) s[nc] = (f32x4){0.f, 0.f, 0.f, 0.f};
#pragma unroll
    for (int nc = 0; nc < 4; nc++)
#pragma unroll
      for (int kt = 0; kt < 4; kt++) {
        bf16x8 kf = *(const bf16x8*)&Ks[cur][(nc * 16 + fr) * 128 + (((kt * 4 + fg) ^ fr) << 3)];
        s[nc] = __builtin_amdgcn_mfma_f32_16x16x32_bf16(qf[kt], kf, s[nc], 0, 0, 0);
      }

    float alpha[4];
#pragma unroll
    for (int j = 0; j < 4; j++) {
      const int qr = q0 + w * 16 + fg * 4 + j;
      float pv[4];
#pragma unroll
      for (int nc = 0; nc < 4; nc++) {
        int kc = kb + nc * 16 + fr;
        float val = s[nc][j];
        if (kc > qr) val = -1e9f;
        pv[nc] = val;
      }
      float tmx = fmaxf(fmaxf(pv[0], pv[1]), fmaxf(pv[2], pv[3]));
      tmx = fmaxf(tmx, __shfl_xor(tmx, 1, 64));
      tmx = fmaxf(tmx, __shfl_xor(tmx, 2, 64));
      tmx = fmaxf(tmx, __shfl_xor(tmx, 4, 64));
      tmx = fmaxf(tmx, __shfl_xor(tmx, 8, 64));
      float mnew = fmaxf(mrow[j], tmx);
      alpha[j] = __expf(mrow[j] - mnew);
      mrow[j] = mnew;
      float rsum = 0.f;
      const int q = fg * 4 + j;
#pragma unroll
      for (int nc = 0; nc < 4; nc++) {
        float e = __expf(pv[nc] - mnew);
        rsum += e;
        Ps[w][q * 64 + (((nc * 2 + (fr >> 3)) ^ (q & 7)) << 3) + (fr & 7)] = (__bf16)e;
      }
      rsum += __shfl_xor(rsum, 1, 64);
      rsum += __shfl_xor(rsum, 2, 64);
      rsum += __shfl_xor(rsum, 4, 64);
      rsum += __shfl_xor(rsum, 8, 64);
      lrow[j] = lrow[j] * alpha[j] + rsum;
    }
#pragma unroll
    for (int nd = 0; nd < 8; nd++)
#pragma unroll
      for (int j = 0; j < 4; j++) o[nd][j] *= alpha[j];

    bf16x8 pa[2];
#pragma unroll
    for (int sl = 0; sl < 2; sl++)
      pa[sl] = *(const bf16x8*)&Ps[w][fr * 64 + (((sl * 4 + fg) ^ (fr & 7)) << 3)];
#pragma unroll
    for (int nd = 0; nd < 8; nd++)
#pragma unroll
      for (int sl = 0; sl < 2; sl++) {
        bf16x8 vf =
            *(const bf16x8*)&Vs[cur][(nd * 16 + fr) * 64 + (((sl * 4 + fg) ^ (fr & 7)) << 3)];
        o[nd] = __builtin_amdgcn_mfma_f32_16x16x32_bf16(pa[sl], vf, o[nd], 0, 0, 0);
      }
    __syncthreads();
  }

  float invl[4];
#pragma unroll
  for (int j = 0; j < 4; j++) invl[j] = 1.0f / lrow[j];
#pragma unroll
  for (int nd = 0; nd < 8; nd++) {
#pragma unroll
    for (int j = 0; j < 4; j++) {
      int row = q0 + w * 16 + fg * 4 + j;
      int d = nd * 16 + fr;
      size_t idx = (size_t)(b * TT + row) * 2048 + h * 128 + d;
      float val = o[nd][j] * invl[j] * (float)Gate[idx];
      Out[idx] = (__bf16)val;
    }
  }
}

// ---------------- host ----------------
extern "C" void kernel_launch(void* const* d_in, const int* in_sizes, int n_in,
                              void* d_out, int out_size, void* d_ws, size_t ws_size,
                              hipStream_t stream) {
  const float* hidden = (const float*)d_in[0];
  const int* posids = (const int*)d_in[2];
  const float* attn_w = (const float*)d_in[3];
  const float* mlp_w = (const float*)d_in[4];
  const float* wq = (const float*)d_in[5];
  const float* wk = (const float*)d_in[6];
  const float* wv = (const float*)d_in[7];
  const float* wo = (const float*)d_in[8];
  const float* gw = (const float*)d_in[9];
  const float* gb = (const float*)d_in[10];
  const float* f1 = (const float*)d_in[11];
  const float* f2 = (const float*)d_in[12];

  char* p = (char*)d_ws;
  auto alloc = [&](size_t n) {
    char* r = p;
    p += (n + 255) & ~(size_t)255;
    return r;
  };
  __bf16* wqg_t = (__bf16*)alloc((size_t)4096 * 2048 * 2);
  __bf16* wkv_t = (__bf16*)alloc((size_t)1024 * 2048 * 2);
  __bf16* wo_t = (__bf16*)alloc((size_t)2048 * 2048 * 2);
  __bf16* f1_t = (__bf16*)alloc((size_t)NI * 2048 * 2);  // reused as fc2 partials
  __bf16* f2_t = (__bf16*)alloc((size_t)2048 * NI * 2);
  __bf16* h_bf = (__bf16*)alloc((size_t)MM * DD * 2);
  float* h1 = (float*)alloc((size_t)MM * 2048 * 4);

  char* regionA = alloc((size_t)64 * 1024 * 1024);
  __bf16* q_bf = (__bf16*)(regionA);
  __bf16* gate_bf = (__bf16*)(regionA + (size_t)16 * 1024 * 1024);
  __bf16* attn_g = (__bf16*)(regionA + (size_t)32 * 1024 * 1024);
  __bf16* k_bf = (__bf16*)(regionA + (size_t)48 * 1024 * 1024);
  __bf16* v_bf = (__bf16*)(regionA + (size_t)52 * 1024 * 1024);
  __bf16* v_t = (__bf16*)(regionA + (size_t)56 * 1024 * 1024);
  float* cosT = (float*)(regionA + (size_t)60 * 1024 * 1024);
  float* sinT = (float*)(regionA + (size_t)62 * 1024 * 1024);
  __bf16* mlp1 = (__bf16*)(regionA);
  __bf16* parts_wo = (__bf16*)(regionA);  // 32 MiB; q_bf/gate_bf dead after attn
  __bf16* parts_fc2 = (__bf16*)f1_t;      // 32 MiB; f1_t dead after fc1

  rope_tables_k<<<4096, 128, 0, stream>>>(cosT, sinT);

  transpose_to_bf16_k<float><<<dim3(64, 64), 256, 0, stream>>>(wq, wqg_t, 2048, 2048);
  transpose_to_bf16_k<float><<<dim3(64, 64), 256, 0, stream>>>(gw, wqg_t + (size_t)2048 * 2048, 2048, 2048);
  transpose_to_bf16_k<float><<<dim3(16, 64), 256, 0, stream>>>(wk, wkv_t, 2048, 512);
  transpose_to_bf16_k<float><<<dim3(16, 64), 256, 0, stream>>>(wv, wkv_t + (size_t)512 * 2048, 2048, 512);
  transpose_to_bf16_k<float><<<dim3(64, 64), 256, 0, stream>>>(wo, wo_t, 2048, 2048);
  transpose_to_bf16_k<float><<<dim3(256, 64), 256, 0, stream>>>(f1, f1_t, 2048, NI);
  transpose_to_bf16_k<float><<<dim3(64, 256), 256, 0, stream>>>(f2, f2_t, NI, 2048);

  rmsnorm_k<<<MM, 256, 0, stream>>>(hidden, attn_w, h_bf);

  const float qsc = 0.08838834764831845f;  // 1/sqrt(128)
  // fused q+gate (champion)
  gemm256_k<G_QG><<<dim3(16, 16), 512, 0, stream>>>(
      h_bf, wqg_t, nullptr, nullptr, q_bf, gate_bf, gb, nullptr, cosT, sinT, posids,
      4096, 2048, 2048, qsc);
  // fused k+v
  gemm_kv_k<<<dim3(8, 32), 256, 0, stream>>>(h_bf, wkv_t, k_bf, v_bf, cosT, sinT, posids, 2048);

  transpose_to_bf16_k<__bf16><<<dim3(16, 128), 256, 0, stream>>>(v_bf, v_t, MM, 512);

  attn_k<<<dim3(32, 32), 256, 0, stream>>>(q_bf, k_bf, v_t, gate_bf, attn_g);

  // wo split-K (z=2) -> bf16 partials (champion), fused combine+RMSNorm
  gemm256_k<G_PART><<<dim3(8, 16, 2), 512, 0, stream>>>(
      attn_g, wo_t, parts_wo, nullptr, nullptr, nullptr, nullptr, nullptr, nullptr, nullptr,
      nullptr, 2048, 1024, 2048, 1.0f);
  combine_rms_k<<<MM, 256, 0, stream>>>(parts_wo, hidden, mlp_w, h1, h_bf);

  // fc1 + SiLU: BK=64 v3 low-VGPR experimental (A/B vs fc2 control)
  gemm256x64_k<G_SILU><<<dim3(32, 16), 512, 0, stream>>>(
      h_bf, f1_t, mlp1, nullptr, nullptr, nullptr, nullptr, nullptr, nullptr, nullptr, nullptr,
      NI, 2048, 2048, 1.0f);

  // fc2 split-K (z=2) -> bf16 partials (champion = control)
  gemm256_k<G_PART><<<dim3(8, 16, 2), 512, 0, stream>>>(
      mlp1, f2_t, parts_fc2, nullptr, nullptr, nullptr, nullptr, nullptr, nullptr, nullptr,
      nullptr, 2048, 4096, NI, 1.0f);

  // d_out = part0 + part1 + h1
  combine_k<<<4096, 256, 0, stream>>>(parts_fc2, h1, (float*)d_out);
}

// Round 14
// 785.364 us; speedup vs baseline: 1.6852x; 1.6852x over previous
//
#include <hip/hip_runtime.h>
#include <hip/hip_bf16.h>
#include <cstdint>
#include <cstddef>

#define BB 2
#define TT 2048
#define DD 2048
#define NH 16
#define NKV 4
#define HD 128
#define NI 8192
#define MM (BB*TT)

typedef __bf16 bf16x8 __attribute__((ext_vector_type(8)));
typedef float  f32x4  __attribute__((ext_vector_type(4)));

__device__ __forceinline__ void gload_lds16(const void* g, void* l) {
  __builtin_amdgcn_global_load_lds((__attribute__((address_space(1))) void*)g,
                                   (__attribute__((address_space(3))) void*)l,
                                   16, 0, 0);
}

// bijective XCD swizzle (m204)
__device__ __forceinline__ int xcd_swizzle(int wg, int nwg) {
  int xcd = wg & 7;
  int l = wg >> 3;
  int q = nwg >> 3, r = nwg & 7;
  return (xcd < r ? xcd * (q + 1) : r * (q + 1) + (xcd - r) * q) + l;
}

// ---------------- RoPE tables ----------------
__global__ __launch_bounds__(128) void rope_tables_k(float* __restrict__ cosT,
                                                     float* __restrict__ sinT) {
  int pos = blockIdx.x;
  int d = threadIdx.x;
  int f = d & 63;
  float inv = powf(10000.0f, -((float)(2 * f)) / 128.0f);
  float ang = inv * (float)pos;
  cosT[pos * 128 + d] = cosf(ang);
  sinT[pos * 128 + d] = sinf(ang);
}

// ---------------- transpose + convert to bf16 ----------------
template <typename TIN>
__global__ __launch_bounds__(256) void transpose_to_bf16_k(const TIN* __restrict__ in,
                                                           __bf16* __restrict__ out,
                                                           int R, int C) {
  __shared__ float t[32][33];
  int c0 = blockIdx.x * 32, r0 = blockIdx.y * 32;
  int tx = threadIdx.x & 31;
  int ty = threadIdx.x >> 5;
#pragma unroll
  for (int i = 0; i < 4; i++) {
    int r = ty + i * 8;
    t[r][tx] = (float)in[(size_t)(r0 + r) * C + c0 + tx];
  }
  __syncthreads();
#pragma unroll
  for (int i = 0; i < 4; i++) {
    int r = ty + i * 8;
    out[(size_t)(c0 + r) * R + r0 + tx] = (__bf16)t[tx][r];
  }
}

// ---------------- RMSNorm ----------------
__global__ __launch_bounds__(256) void rmsnorm_k(const float* __restrict__ x,
                                                 const float* __restrict__ w,
                                                 __bf16* __restrict__ out) {
  int row = blockIdx.x;
  const float* xr = x + (size_t)row * DD;
  int t = threadIdx.x;
  float4 a = ((const float4*)xr)[2 * t];
  float4 b = ((const float4*)xr)[2 * t + 1];
  float ss = a.x * a.x + a.y * a.y + a.z * a.z + a.w * a.w +
             b.x * b.x + b.y * b.y + b.z * b.z + b.w * b.w;
#pragma unroll
  for (int off = 32; off; off >>= 1) ss += __shfl_xor(ss, off, 64);
  __shared__ float red[4];
  if ((t & 63) == 0) red[t >> 6] = ss;
  __syncthreads();
  float tot = red[0] + red[1] + red[2] + red[3];
  float rs = rsqrtf(tot * (1.0f / DD) + 1e-6f);
  const float4 w1 = ((const float4*)w)[2 * t];
  const float4 w2 = ((const float4*)w)[2 * t + 1];
  bf16x8 ov;
  ov[0] = (__bf16)(a.x * rs * w1.x);
  ov[1] = (__bf16)(a.y * rs * w1.y);
  ov[2] = (__bf16)(a.z * rs * w1.z);
  ov[3] = (__bf16)(a.w * rs * w1.w);
  ov[4] = (__bf16)(b.x * rs * w2.x);
  ov[5] = (__bf16)(b.y * rs * w2.y);
  ov[6] = (__bf16)(b.z * rs * w2.z);
  ov[7] = (__bf16)(b.w * rs * w2.w);
  *(bf16x8*)(out + (size_t)row * DD + t * 8) = ov;
}

// ---------------- GEMM 256x256, BK=32, 3-buffer ring, 2 phases/K-step (champion) ----------------
enum { G_QG = 0, G_RES = 1, G_SILU = 2, G_PART = 3 };

template <int EPI>
__global__ __launch_bounds__(512) void gemm256_k(
    const __bf16* __restrict__ A, const __bf16* __restrict__ Bt,
    __bf16* __restrict__ outB, float* __restrict__ outF,
    __bf16* __restrict__ outQ, __bf16* __restrict__ outG,
    const float* __restrict__ bias, const float* __restrict__ residual,
    const float* __restrict__ cosT, const float* __restrict__ sinT,
    const int* __restrict__ posids, int N, int K, int ldk, float oscale) {
  __shared__ __align__(16) __bf16 Ab[3][256 * 32];
  __shared__ __align__(16) __bf16 Bb[3][256 * 32];
  const int tid = threadIdx.x;
  const int lane = tid & 63;
  const int wid = tid >> 6;
  const int wr = wid >> 2;  // 0..1
  const int wc = wid & 3;   // 0..3
  const int fr = lane & 15;
  const int fg = lane >> 4;

  const int nwg = gridDim.x * gridDim.y;
  int wg = xcd_swizzle(blockIdx.y * gridDim.x + blockIdx.x, nwg);
  const int bx = wg % gridDim.x, by = wg / gridDim.x;
  const int m0 = by * 256;
  const int n0 = bx * 256;
  const int kz = blockIdx.z;
  const int kBase = kz * K;

  const int srow0 = wid * 32 + (lane >> 2);
  const int scol = (((lane & 3) ^ ((lane >> 3) & 3)) << 3);  // pre-swizzled source slot
  const __bf16* aS0 = A + (size_t)(m0 + srow0) * ldk + kBase + scol;
  const __bf16* aS1 = aS0 + (size_t)16 * ldk;
  const __bf16* bS0 = Bt + (size_t)(n0 + srow0) * ldk + kBase + scol;
  const __bf16* bS1 = bS0 + (size_t)16 * ldk;
  const int e0 = (wid * 2) * 512;
  const int e1 = (wid * 2 + 1) * 512;

  const int nt = K / 32;

#define STAGE_A(kt, s)                          \
  {                                             \
    const int k0_ = (kt) * 32;                  \
    gload_lds16(aS0 + k0_, &Ab[(s)][e0]);       \
    gload_lds16(aS1 + k0_, &Ab[(s)][e1]);       \
  }
#define STAGE_B(kt, s)                          \
  {                                             \
    const int k0_ = (kt) * 32;                  \
    gload_lds16(bS0 + k0_, &Bb[(s)][e0]);       \
    gload_lds16(bS1 + k0_, &Bb[(s)][e1]);       \
  }

  STAGE_A(0, 0);
  STAGE_B(0, 0);
  STAGE_A(1, 1);
  STAGE_B(1, 1);
  asm volatile("s_waitcnt vmcnt(4)" ::: "memory");
  __builtin_amdgcn_s_barrier();

  f32x4 acc[8][4];
#pragma unroll
  for (int i = 0; i < 8; i++)
#pragma unroll
    for (int j = 0; j < 4; j++) acc[i][j] = (f32x4){0.f, 0.f, 0.f, 0.f};

  const int asl = (fg ^ ((fr >> 1) & 3)) * 8;  // swizzled 16B-slot for fragment reads

  for (int t = 0; t < nt; ++t) {
    const int s = t % 3;
    const int sn = (t + 2) % 3;
    // ---- phase 1 ----
    bf16x8 af[4], bfr[4];
#pragma unroll
    for (int mi = 0; mi < 4; mi++)
      af[mi] = *(const bf16x8*)&Ab[s][(wr * 128 + mi * 16 + fr) * 32 + asl];
#pragma unroll
    for (int ni = 0; ni < 4; ni++)
      bfr[ni] = *(const bf16x8*)&Bb[s][(wc * 64 + ni * 16 + fr) * 32 + asl];
    if (t + 2 < nt) STAGE_A(t + 2, sn);
    __builtin_amdgcn_s_barrier();
    asm volatile("s_waitcnt lgkmcnt(0)" ::: "memory");
    __builtin_amdgcn_sched_barrier(0);
    __builtin_amdgcn_s_setprio(1);
#pragma unroll
    for (int mi = 0; mi < 4; mi++)
#pragma unroll
      for (int ni = 0; ni < 4; ni++)
        acc[mi][ni] =
            __builtin_amdgcn_mfma_f32_16x16x32_bf16(af[mi], bfr[ni], acc[mi][ni], 0, 0, 0);
    __builtin_amdgcn_s_setprio(0);
    __builtin_amdgcn_s_barrier();
    // ---- phase 2 (vmcnt wait after MFMA cluster) ----
    bf16x8 af2[4];
#pragma unroll
    for (int mi = 0; mi < 4; mi++)
      af2[mi] = *(const bf16x8*)&Ab[s][(wr * 128 + (mi + 4) * 16 + fr) * 32 + asl];
    if (t + 2 < nt) STAGE_B(t + 2, sn);
    __builtin_amdgcn_s_barrier();
    asm volatile("s_waitcnt lgkmcnt(0)" ::: "memory");
    __builtin_amdgcn_sched_barrier(0);
    __builtin_amdgcn_s_setprio(1);
#pragma unroll
    for (int mi = 0; mi < 4; mi++)
#pragma unroll
      for (int ni = 0; ni < 4; ni++)
        acc[mi + 4][ni] =
            __builtin_amdgcn_mfma_f32_16x16x32_bf16(af2[mi], bfr[ni], acc[mi + 4][ni], 0, 0, 0);
    __builtin_amdgcn_s_setprio(0);
    if (t + 2 < nt) {
      asm volatile("s_waitcnt vmcnt(4)" ::: "memory");
    } else {
      asm volatile("s_waitcnt vmcnt(0)" ::: "memory");
    }
    __builtin_amdgcn_s_barrier();
  }
#undef STAGE_A
#undef STAGE_B

  // epilogue
#pragma unroll
  for (int mi = 0; mi < 8; mi++) {
    const int row = m0 + wr * 128 + mi * 16 + fg * 4;
#pragma unroll
    for (int ni = 0; ni < 4; ni++) {
      const int col = n0 + wc * 64 + ni * 16 + fr;
#pragma unroll
      for (int j = 0; j < 4; j++) {
        float v = acc[mi][ni][j];
        const int r = row + j;
        if constexpr (EPI == G_QG) {
          float vp = __shfl_xor(v, 1, 64);
          if (n0 < 2048) {
            int pos = posids[r];
            int d = col & 127;
            float c = cosT[pos * 128 + d], sn2 = sinT[pos * 128 + d];
            float o = (col & 1) ? (v * c + vp * sn2) : (v * c - vp * sn2);
            outQ[(size_t)r * 2048 + col] = (__bf16)(o * oscale);
          } else {
            float xx = v + bias[col - 2048];
            outG[(size_t)r * 2048 + (col - 2048)] = (__bf16)(1.0f / (1.0f + expf(-xx)));
          }
        } else if constexpr (EPI == G_RES) {
          outF[(size_t)r * N + col] = v + residual[(size_t)r * N + col];
        } else if constexpr (EPI == G_SILU) {
          outB[(size_t)r * N + col] = (__bf16)(v / (1.0f + expf(-v)));
        } else {
          outB[(size_t)(kz * MM + r) * N + col] = (__bf16)v;
        }
      }
    }
  }
}

// ---------------- combine: out = part0 + part1 + res (f32) ----------------
__global__ __launch_bounds__(256) void combine_k(const __bf16* __restrict__ parts,
                                                 const float* __restrict__ res,
                                                 float* __restrict__ out) {
  size_t i = ((size_t)blockIdx.x * 256 + threadIdx.x) * 8;
  bf16x8 p0 = *(const bf16x8*)&parts[i];
  bf16x8 p1 = *(const bf16x8*)&parts[(size_t)MM * 2048 + i];
  float4 a = *(const float4*)&res[i];
  float4 b = *(const float4*)&res[i + 4];
  float4 o0, o1;
  o0.x = (float)p0[0] + (float)p1[0] + a.x;
  o0.y = (float)p0[1] + (float)p1[1] + a.y;
  o0.z = (float)p0[2] + (float)p1[2] + a.z;
  o0.w = (float)p0[3] + (float)p1[3] + a.w;
  o1.x = (float)p0[4] + (float)p1[4] + b.x;
  o1.y = (float)p0[5] + (float)p1[5] + b.y;
  o1.z = (float)p0[6] + (float)p1[6] + b.z;
  o1.w = (float)p0[7] + (float)p1[7] + b.w;
  *(float4*)&out[i] = o0;
  *(float4*)&out[i + 4] = o1;
}

// ---------------- fused combine + RMSNorm ----------------
__global__ __launch_bounds__(256) void combine_rms_k(const __bf16* __restrict__ parts,
                                                     const float* __restrict__ res,
                                                     const float* __restrict__ w,
                                                     float* __restrict__ h1,
                                                     __bf16* __restrict__ h2) {
  const int row = blockIdx.x;
  const int t = threadIdx.x;
  const size_t i = (size_t)row * 2048 + t * 8;
  bf16x8 p0 = *(const bf16x8*)&parts[i];
  bf16x8 p1 = *(const bf16x8*)&parts[(size_t)MM * 2048 + i];
  float4 a = *(const float4*)&res[i];
  float4 b = *(const float4*)&res[i + 4];
  float v[8];
  v[0] = (float)p0[0] + (float)p1[0] + a.x;
  v[1] = (float)p0[1] + (float)p1[1] + a.y;
  v[2] = (float)p0[2] + (float)p1[2] + a.z;
  v[3] = (float)p0[3] + (float)p1[3] + a.w;
  v[4] = (float)p0[4] + (float)p1[4] + b.x;
  v[5] = (float)p0[5] + (float)p1[5] + b.y;
  v[6] = (float)p0[6] + (float)p1[6] + b.z;
  v[7] = (float)p0[7] + (float)p1[7] + b.w;
  float4 o0 = {v[0], v[1], v[2], v[3]};
  float4 o1 = {v[4], v[5], v[6], v[7]};
  *(float4*)&h1[i] = o0;
  *(float4*)&h1[i + 4] = o1;
  float ss = 0.f;
#pragma unroll
  for (int k = 0; k < 8; k++) ss += v[k] * v[k];
#pragma unroll
  for (int off = 32; off; off >>= 1) ss += __shfl_xor(ss, off, 64);
  __shared__ float red[4];
  if ((t & 63) == 0) red[t >> 6] = ss;
  __syncthreads();
  float tot = red[0] + red[1] + red[2] + red[3];
  float rs = rsqrtf(tot * (1.0f / DD) + 1e-6f);
  const float4 w1 = ((const float4*)w)[2 * t];
  const float4 w2 = ((const float4*)w)[2 * t + 1];
  bf16x8 ov;
  ov[0] = (__bf16)(v[0] * rs * w1.x);
  ov[1] = (__bf16)(v[1] * rs * w1.y);
  ov[2] = (__bf16)(v[2] * rs * w1.z);
  ov[3] = (__bf16)(v[3] * rs * w1.w);
  ov[4] = (__bf16)(v[4] * rs * w2.x);
  ov[5] = (__bf16)(v[5] * rs * w2.y);
  ov[6] = (__bf16)(v[6] * rs * w2.z);
  ov[7] = (__bf16)(v[7] * rs * w2.w);
  *(bf16x8*)(h2 + i) = ov;
}

// ---------------- K+V fused projection (128x128 tile) ----------------
__global__ __launch_bounds__(256) void gemm_kv_k(
    const __bf16* __restrict__ A, const __bf16* __restrict__ Bt,
    __bf16* __restrict__ kOut, __bf16* __restrict__ vOut,
    const float* __restrict__ cosT, const float* __restrict__ sinT,
    const int* __restrict__ posids, int K) {
  __shared__ __align__(16) __bf16 As[128 * 32];
  __shared__ __align__(16) __bf16 Bs[128 * 32];
  const int tid = threadIdx.x;
  const int lane = tid & 63;
  const int w = tid >> 6;
  const int wm = w >> 1, wn = w & 1;

  const int nwg = gridDim.x * gridDim.y;
  int wg = xcd_swizzle(blockIdx.y * gridDim.x + blockIdx.x, nwg);
  const int bx = wg % gridDim.x, by = wg / gridDim.x;
  const int m0 = by * 128;
  const int n0 = bx * 128;

  const int lr = lane >> 2;
  const int lc = (lane & 3) * 8;
  const __bf16* aSrc = A + (size_t)(m0 + 32 * w + lr) * K + lc;
  const __bf16* bSrc = Bt + (size_t)(n0 + 32 * w + lr) * K + lc;
  __bf16* aDst = &As[w * 1024];
  __bf16* bDst = &Bs[w * 1024];

  f32x4 acc[4][4];
#pragma unroll
  for (int i = 0; i < 4; i++)
#pragma unroll
    for (int j = 0; j < 4; j++) acc[i][j] = (f32x4){0.f, 0.f, 0.f, 0.f};

  const int fr = lane & 15;
  const int fc = (lane >> 4) * 8;

  for (int k0 = 0; k0 < K; k0 += 32) {
    __syncthreads();
    gload_lds16(aSrc + k0, aDst);
    gload_lds16(aSrc + k0 + (size_t)16 * K, aDst + 512);
    gload_lds16(bSrc + k0, bDst);
    gload_lds16(bSrc + k0 + (size_t)16 * K, bDst + 512);
    asm volatile("s_waitcnt vmcnt(0)" ::: "memory");
    __syncthreads();

    bf16x8 af[4], bfg[4];
#pragma unroll
    for (int i = 0; i < 4; i++)
      af[i] = *(const bf16x8*)&As[(wm * 64 + i * 16 + fr) * 32 + fc];
#pragma unroll
    for (int i = 0; i < 4; i++)
      bfg[i] = *(const bf16x8*)&Bs[(wn * 64 + i * 16 + fr) * 32 + fc];
#pragma unroll
    for (int mi = 0; mi < 4; mi++)
#pragma unroll
      for (int ni = 0; ni < 4; ni++)
        acc[mi][ni] =
            __builtin_amdgcn_mfma_f32_16x16x32_bf16(af[mi], bfg[ni], acc[mi][ni], 0, 0, 0);
  }

  const int fg = lane >> 4;
#pragma unroll
  for (int mi = 0; mi < 4; mi++) {
#pragma unroll
    for (int ni = 0; ni < 4; ni++) {
#pragma unroll
      for (int j = 0; j < 4; j++) {
        int row = m0 + wm * 64 + mi * 16 + fg * 4 + j;
        int col = n0 + wn * 64 + ni * 16 + fr;
        float v = acc[mi][ni][j];
        float vp = __shfl_xor(v, 1, 64);
        if (col < 512) {  // k: rope
          int pos = posids[row];
          int d = col & 127;
          float c = cosT[pos * 128 + d];
          float s = sinT[pos * 128 + d];
          float o = (col & 1) ? (v * c + vp * s) : (v * c - vp * s);
          kOut[(size_t)row * 512 + col] = (__bf16)o;
        } else {  // v: plain
          vOut[(size_t)row * 512 + (col - 512)] = (__bf16)v;
        }
      }
    }
  }
}

// ---------------- Flash attention (verified) ----------------
__global__ __launch_bounds__(256) void attn_k(const __bf16* __restrict__ Q,
                                              const __bf16* __restrict__ Kb,
                                              const __bf16* __restrict__ Vt,
                                              const __bf16* __restrict__ Gate,
                                              __bf16* __restrict__ Out) {
  __shared__ __align__(16) __bf16 Ks[2][64 * 128];
  __shared__ __align__(16) __bf16 Vs[2][128 * 64];
  __shared__ __align__(16) __bf16 Ps[4][16 * 64];
  const int tid = threadIdx.x;
  const int lane = tid & 63;
  const int w = tid >> 6;
  const int fr = lane & 15;
  const int fg = lane >> 4;

  const int nwg = gridDim.x * gridDim.y;
  int wg = xcd_swizzle(blockIdx.y * gridDim.x + blockIdx.x, nwg);
  const int qb = wg % gridDim.x;
  const int bh = wg / gridDim.x;
  const int q0 = qb * 64;
  const int b = bh >> 4, h = bh & 15;
  const int g = h >> 2;

  const size_t qrow = (size_t)(b * TT + q0 + w * 16 + fr);
  bf16x8 qf[4];
#pragma unroll
  for (int kt = 0; kt < 4; kt++)
    qf[kt] = *(const bf16x8*)&Q[qrow * 2048 + h * 128 + kt * 32 + fg * 8];

  const __bf16* kPtr[4];
  const __bf16* vPtr[4];
#pragma unroll
  for (int i = 0; i < 4; i++) {
    int krow = w * 16 + i * 4 + (lane >> 4);
    int kcol8 = (lane & 15) ^ (krow & 15);
    kPtr[i] = Kb + (size_t)(b * TT + krow) * 512 + g * 128 + kcol8 * 8;
    int dloc = w * 32 + i * 8 + (lane >> 3);
    int kv8 = (lane & 7) ^ (dloc & 7);
    vPtr[i] = Vt + (size_t)(g * 128 + dloc) * (size_t)MM + b * TT + kv8 * 8;
  }

  f32x4 o[8];
#pragma unroll
  for (int i = 0; i < 8; i++) o[i] = (f32x4){0.f, 0.f, 0.f, 0.f};
  float mrow[4] = {-3e38f, -3e38f, -3e38f, -3e38f};
  float lrow[4] = {0.f, 0.f, 0.f, 0.f};

  const int nsteps = qb + 1;

#pragma unroll
  for (int i = 0; i < 4; i++) {
    gload_lds16(kPtr[i], &Ks[0][w * 2048 + i * 512]);
    gload_lds16(vPtr[i], &Vs[0][w * 2048 + i * 512]);
  }
  __syncthreads();

  for (int t = 0; t < nsteps; t++) {
    const int cur = t & 1;
    const int kb = t * 64;
    if (t + 1 < nsteps) {
      const int nb = kb + 64;
#pragma unroll
      for (int i = 0; i < 4; i++) {
        gload_lds16(kPtr[i] + (size_t)nb * 512, &Ks[cur ^ 1][w * 2048 + i * 512]);
        gload_lds16(vPtr[i] + nb, &Vs[cur ^ 1][w * 2048 + i * 512]);
      }
    }

    f32x4 s[4];
#pragma unroll
    for (int nc = 0; nc < 4; nc++) s[nc] = (f32x4){0.f, 0.f, 0.f, 0.f};
#pragma unroll
    for (int nc = 0; nc < 4; nc++)
#pragma unroll
      for (int kt = 0; kt < 4; kt++) {
        bf16x8 kf = *(const bf16x8*)&Ks[cur][(nc * 16 + fr) * 128 + (((kt * 4 + fg) ^ fr) << 3)];
        s[nc] = __builtin_amdgcn_mfma_f32_16x16x32_bf16(qf[kt], kf, s[nc], 0, 0, 0);
      }

    float alpha[4];
#pragma unroll
    for (int j = 0; j < 4; j++) {
      const int qr = q0 + w * 16 + fg * 4 + j;
      float pv[4];
#pragma unroll
      for (int nc = 0; nc < 4; nc++) {
        int kc = kb + nc * 16 + fr;
        float val = s[nc][j];
        if (kc > qr) val = -1e9f;
        pv[nc] = val;
      }
      float tmx = fmaxf(fmaxf(pv[0], pv[1]), fmaxf(pv[2], pv[3]));
      tmx = fmaxf(tmx, __shfl_xor(tmx, 1, 64));
      tmx = fmaxf(tmx, __shfl_xor(tmx, 2, 64));
      tmx = fmaxf(tmx, __shfl_xor(tmx, 4, 64));
      tmx = fmaxf(tmx, __shfl_xor(tmx, 8, 64));
      float mnew = fmaxf(mrow[j], tmx);
      alpha[j] = __expf(mrow[j] - mnew);
      mrow[j] = mnew;
      float rsum = 0.f;
      const int q = fg * 4 + j;
#pragma unroll
      for (int nc = 0; nc < 4; nc++) {
        float e = __expf(pv[nc] - mnew);
        rsum += e;
        Ps[w][q * 64 + (((nc * 2 + (fr >> 3)) ^ (q & 7)) << 3) + (fr & 7)] = (__bf16)e;
      }
      rsum += __shfl_xor(rsum, 1, 64);
      rsum += __shfl_xor(rsum, 2, 64);
      rsum += __shfl_xor(rsum, 4, 64);
      rsum += __shfl_xor(rsum, 8, 64);
      lrow[j] = lrow[j] * alpha[j] + rsum;
    }
#pragma unroll
    for (int nd = 0; nd < 8; nd++)
#pragma unroll
      for (int j = 0; j < 4; j++) o[nd][j] *= alpha[j];

    bf16x8 pa[2];
#pragma unroll
    for (int sl = 0; sl < 2; sl++)
      pa[sl] = *(const bf16x8*)&Ps[w][fr * 64 + (((sl * 4 + fg) ^ (fr & 7)) << 3)];
#pragma unroll
    for (int nd = 0; nd < 8; nd++)
#pragma unroll
      for (int sl = 0; sl < 2; sl++) {
        bf16x8 vf =
            *(const bf16x8*)&Vs[cur][(nd * 16 + fr) * 64 + (((sl * 4 + fg) ^ (fr & 7)) << 3)];
        o[nd] = __builtin_amdgcn_mfma_f32_16x16x32_bf16(pa[sl], vf, o[nd], 0, 0, 0);
      }
    __syncthreads();
  }

  float invl[4];
#pragma unroll
  for (int j = 0; j < 4; j++) invl[j] = 1.0f / lrow[j];
#pragma unroll
  for (int nd = 0; nd < 8; nd++) {
#pragma unroll
    for (int j = 0; j < 4; j++) {
      int row = q0 + w * 16 + fg * 4 + j;
      int d = nd * 16 + fr;
      size_t idx = (size_t)(b * TT + row) * 2048 + h * 128 + d;
      float val = o[nd][j] * invl[j] * (float)Gate[idx];
      Out[idx] = (__bf16)val;
    }
  }
}

// ---------------- host ----------------
extern "C" void kernel_launch(void* const* d_in, const int* in_sizes, int n_in,
                              void* d_out, int out_size, void* d_ws, size_t ws_size,
                              hipStream_t stream) {
  const float* hidden = (const float*)d_in[0];
  const int* posids = (const int*)d_in[2];
  const float* attn_w = (const float*)d_in[3];
  const float* mlp_w = (const float*)d_in[4];
  const float* wq = (const float*)d_in[5];
  const float* wk = (const float*)d_in[6];
  const float* wv = (const float*)d_in[7];
  const float* wo = (const float*)d_in[8];
  const float* gw = (const float*)d_in[9];
  const float* gb = (const float*)d_in[10];
  const float* f1 = (const float*)d_in[11];
  const float* f2 = (const float*)d_in[12];

  char* p = (char*)d_ws;
  auto alloc = [&](size_t n) {
    char* r = p;
    p += (n + 255) & ~(size_t)255;
    return r;
  };
  __bf16* wqg_t = (__bf16*)alloc((size_t)4096 * 2048 * 2);
  __bf16* wkv_t = (__bf16*)alloc((size_t)1024 * 2048 * 2);
  __bf16* wo_t = (__bf16*)alloc((size_t)2048 * 2048 * 2);
  __bf16* f1_t = (__bf16*)alloc((size_t)NI * 2048 * 2);  // reused as fc2 partials
  __bf16* f2_t = (__bf16*)alloc((size_t)2048 * NI * 2);
  __bf16* h_bf = (__bf16*)alloc((size_t)MM * DD * 2);
  float* h1 = (float*)alloc((size_t)MM * 2048 * 4);

  char* regionA = alloc((size_t)64 * 1024 * 1024);
  __bf16* q_bf = (__bf16*)(regionA);
  __bf16* gate_bf = (__bf16*)(regionA + (size_t)16 * 1024 * 1024);
  __bf16* attn_g = (__bf16*)(regionA + (size_t)32 * 1024 * 1024);
  __bf16* k_bf = (__bf16*)(regionA + (size_t)48 * 1024 * 1024);
  __bf16* v_bf = (__bf16*)(regionA + (size_t)52 * 1024 * 1024);
  __bf16* v_t = (__bf16*)(regionA + (size_t)56 * 1024 * 1024);
  float* cosT = (float*)(regionA + (size_t)60 * 1024 * 1024);
  float* sinT = (float*)(regionA + (size_t)62 * 1024 * 1024);
  __bf16* mlp1 = (__bf16*)(regionA);
  __bf16* parts_wo = (__bf16*)(regionA);  // 32 MiB; q_bf/gate_bf dead after attn
  __bf16* parts_fc2 = (__bf16*)f1_t;      // 32 MiB; f1_t dead after fc1

  rope_tables_k<<<4096, 128, 0, stream>>>(cosT, sinT);

  transpose_to_bf16_k<float><<<dim3(64, 64), 256, 0, stream>>>(wq, wqg_t, 2048, 2048);
  transpose_to_bf16_k<float><<<dim3(64, 64), 256, 0, stream>>>(gw, wqg_t + (size_t)2048 * 2048, 2048, 2048);
  transpose_to_bf16_k<float><<<dim3(16, 64), 256, 0, stream>>>(wk, wkv_t, 2048, 512);
  transpose_to_bf16_k<float><<<dim3(16, 64), 256, 0, stream>>>(wv, wkv_t + (size_t)512 * 2048, 2048, 512);
  transpose_to_bf16_k<float><<<dim3(64, 64), 256, 0, stream>>>(wo, wo_t, 2048, 2048);
  transpose_to_bf16_k<float><<<dim3(256, 64), 256, 0, stream>>>(f1, f1_t, 2048, NI);
  transpose_to_bf16_k<float><<<dim3(64, 256), 256, 0, stream>>>(f2, f2_t, NI, 2048);

  rmsnorm_k<<<MM, 256, 0, stream>>>(hidden, attn_w, h_bf);

  const float qsc = 0.08838834764831845f;  // 1/sqrt(128)
  // fused q+gate
  gemm256_k<G_QG><<<dim3(16, 16), 512, 0, stream>>>(
      h_bf, wqg_t, nullptr, nullptr, q_bf, gate_bf, gb, nullptr, cosT, sinT, posids,
      4096, 2048, 2048, qsc);
  // fused k+v
  gemm_kv_k<<<dim3(8, 32), 256, 0, stream>>>(h_bf, wkv_t, k_bf, v_bf, cosT, sinT, posids, 2048);

  transpose_to_bf16_k<__bf16><<<dim3(16, 128), 256, 0, stream>>>(v_bf, v_t, MM, 512);

  attn_k<<<dim3(32, 32), 256, 0, stream>>>(q_bf, k_bf, v_t, gate_bf, attn_g);

  // wo split-K (z=2) -> bf16 partials, then fused combine + mlp-RMSNorm
  gemm256_k<G_PART><<<dim3(8, 16, 2), 512, 0, stream>>>(
      attn_g, wo_t, parts_wo, nullptr, nullptr, nullptr, nullptr, nullptr, nullptr, nullptr,
      nullptr, 2048, 1024, 2048, 1.0f);
  combine_rms_k<<<MM, 256, 0, stream>>>(parts_wo, hidden, mlp_w, h1, h_bf);

  // fc1 + SiLU
  gemm256_k<G_SILU><<<dim3(32, 16), 512, 0, stream>>>(
      h_bf, f1_t, mlp1, nullptr, nullptr, nullptr, nullptr, nullptr, nullptr, nullptr, nullptr,
      NI, 2048, 2048, 1.0f);

  // fc2 split-K (z=2) -> bf16 partials
  gemm256_k<G_PART><<<dim3(8, 16, 2), 512, 0, stream>>>(
      mlp1, f2_t, parts_fc2, nullptr, nullptr, nullptr, nullptr, nullptr, nullptr, nullptr,
      nullptr, 2048, 4096, NI, 1.0f);

  // d_out = part0 + part1 + h1
  combine_k<<<4096, 256, 0, stream>>>(parts_fc2, h1, (float*)d_out);
}

// Round 15
// 768.858 us; speedup vs baseline: 1.7214x; 1.0215x over previous
//
#include <hip/hip_runtime.h>
#include <hip/hip_bf16.h>
#include <cstdint>
#include <cstddef>

#define BB 2
#define TT 2048
#define DD 2048
#define NH 16
#define NKV 4
#define HD 128
#define NI 8192
#define MM (BB*TT)

typedef __bf16 bf16x8 __attribute__((ext_vector_type(8)));
typedef float  f32x4  __attribute__((ext_vector_type(4)));

__device__ __forceinline__ void gload_lds16(const void* g, void* l) {
  __builtin_amdgcn_global_load_lds((__attribute__((address_space(1))) void*)g,
                                   (__attribute__((address_space(3))) void*)l,
                                   16, 0, 0);
}

// bijective XCD swizzle (m204)
__device__ __forceinline__ int xcd_swizzle(int wg, int nwg) {
  int xcd = wg & 7;
  int l = wg >> 3;
  int q = nwg >> 3, r = nwg & 7;
  return (xcd < r ? xcd * (q + 1) : r * (q + 1) + (xcd - r) * q) + l;
}

// ---------------- RoPE tables ----------------
__global__ __launch_bounds__(128) void rope_tables_k(float* __restrict__ cosT,
                                                     float* __restrict__ sinT) {
  int pos = blockIdx.x;
  int d = threadIdx.x;
  int f = d & 63;
  float inv = powf(10000.0f, -((float)(2 * f)) / 128.0f);
  float ang = inv * (float)pos;
  cosT[pos * 128 + d] = cosf(ang);
  sinT[pos * 128 + d] = sinf(ang);
}

// ---------------- transpose + convert to bf16 ----------------
template <typename TIN>
__global__ __launch_bounds__(256) void transpose_to_bf16_k(const TIN* __restrict__ in,
                                                           __bf16* __restrict__ out,
                                                           int R, int C) {
  __shared__ float t[32][33];
  int c0 = blockIdx.x * 32, r0 = blockIdx.y * 32;
  int tx = threadIdx.x & 31;
  int ty = threadIdx.x >> 5;
#pragma unroll
  for (int i = 0; i < 4; i++) {
    int r = ty + i * 8;
    t[r][tx] = (float)in[(size_t)(r0 + r) * C + c0 + tx];
  }
  __syncthreads();
#pragma unroll
  for (int i = 0; i < 4; i++) {
    int r = ty + i * 8;
    out[(size_t)(c0 + r) * R + r0 + tx] = (__bf16)t[tx][r];
  }
}

// ---------------- RMSNorm ----------------
__global__ __launch_bounds__(256) void rmsnorm_k(const float* __restrict__ x,
                                                 const float* __restrict__ w,
                                                 __bf16* __restrict__ out) {
  int row = blockIdx.x;
  const float* xr = x + (size_t)row * DD;
  int t = threadIdx.x;
  float4 a = ((const float4*)xr)[2 * t];
  float4 b = ((const float4*)xr)[2 * t + 1];
  float ss = a.x * a.x + a.y * a.y + a.z * a.z + a.w * a.w +
             b.x * b.x + b.y * b.y + b.z * b.z + b.w * b.w;
#pragma unroll
  for (int off = 32; off; off >>= 1) ss += __shfl_xor(ss, off, 64);
  __shared__ float red[4];
  if ((t & 63) == 0) red[t >> 6] = ss;
  __syncthreads();
  float tot = red[0] + red[1] + red[2] + red[3];
  float rs = rsqrtf(tot * (1.0f / DD) + 1e-6f);
  const float4 w1 = ((const float4*)w)[2 * t];
  const float4 w2 = ((const float4*)w)[2 * t + 1];
  bf16x8 ov;
  ov[0] = (__bf16)(a.x * rs * w1.x);
  ov[1] = (__bf16)(a.y * rs * w1.y);
  ov[2] = (__bf16)(a.z * rs * w1.z);
  ov[3] = (__bf16)(a.w * rs * w1.w);
  ov[4] = (__bf16)(b.x * rs * w2.x);
  ov[5] = (__bf16)(b.y * rs * w2.y);
  ov[6] = (__bf16)(b.z * rs * w2.z);
  ov[7] = (__bf16)(b.w * rs * w2.w);
  *(bf16x8*)(out + (size_t)row * DD + t * 8) = ov;
}

// ---------------- GEMM 256x256, BK=32, 3-buffer ring, 2 phases/K-step (champion) ----------------
enum { G_QG = 0, G_RES = 1, G_SILU = 2, G_PART = 3 };

template <int EPI>
__global__ __launch_bounds__(512) void gemm256_k(
    const __bf16* __restrict__ A, const __bf16* __restrict__ Bt,
    __bf16* __restrict__ outB, float* __restrict__ outF,
    __bf16* __restrict__ outQ, __bf16* __restrict__ outG,
    const float* __restrict__ bias, const float* __restrict__ residual,
    const float* __restrict__ cosT, const float* __restrict__ sinT,
    const int* __restrict__ posids, int N, int K, int ldk, float oscale) {
  __shared__ __align__(16) __bf16 Ab[3][256 * 32];
  __shared__ __align__(16) __bf16 Bb[3][256 * 32];
  const int tid = threadIdx.x;
  const int lane = tid & 63;
  const int wid = tid >> 6;
  const int wr = wid >> 2;  // 0..1
  const int wc = wid & 3;   // 0..3
  const int fr = lane & 15;
  const int fg = lane >> 4;

  const int nwg = gridDim.x * gridDim.y;
  int wg = xcd_swizzle(blockIdx.y * gridDim.x + blockIdx.x, nwg);
  const int bx = wg % gridDim.x, by = wg / gridDim.x;
  const int m0 = by * 256;
  const int n0 = bx * 256;
  const int kz = blockIdx.z;
  const int kBase = kz * K;

  const int srow0 = wid * 32 + (lane >> 2);
  const int scol = (((lane & 3) ^ ((lane >> 3) & 3)) << 3);  // pre-swizzled source slot
  const __bf16* aS0 = A + (size_t)(m0 + srow0) * ldk + kBase + scol;
  const __bf16* aS1 = aS0 + (size_t)16 * ldk;
  const __bf16* bS0 = Bt + (size_t)(n0 + srow0) * ldk + kBase + scol;
  const __bf16* bS1 = bS0 + (size_t)16 * ldk;
  const int e0 = (wid * 2) * 512;
  const int e1 = (wid * 2 + 1) * 512;

  const int nt = K / 32;

#define STAGE_A(kt, s)                          \
  {                                             \
    const int k0_ = (kt) * 32;                  \
    gload_lds16(aS0 + k0_, &Ab[(s)][e0]);       \
    gload_lds16(aS1 + k0_, &Ab[(s)][e1]);       \
  }
#define STAGE_B(kt, s)                          \
  {                                             \
    const int k0_ = (kt) * 32;                  \
    gload_lds16(bS0 + k0_, &Bb[(s)][e0]);       \
    gload_lds16(bS1 + k0_, &Bb[(s)][e1]);       \
  }

  STAGE_A(0, 0);
  STAGE_B(0, 0);
  STAGE_A(1, 1);
  STAGE_B(1, 1);
  asm volatile("s_waitcnt vmcnt(4)" ::: "memory");
  __builtin_amdgcn_s_barrier();

  f32x4 acc[8][4];
#pragma unroll
  for (int i = 0; i < 8; i++)
#pragma unroll
    for (int j = 0; j < 4; j++) acc[i][j] = (f32x4){0.f, 0.f, 0.f, 0.f};

  const int asl = (fg ^ ((fr >> 1) & 3)) * 8;  // swizzled 16B-slot for fragment reads

  for (int t = 0; t < nt; ++t) {
    const int s = t % 3;
    const int sn = (t + 2) % 3;
    // ---- phase 1 ----
    bf16x8 af[4], bfr[4];
#pragma unroll
    for (int mi = 0; mi < 4; mi++)
      af[mi] = *(const bf16x8*)&Ab[s][(wr * 128 + mi * 16 + fr) * 32 + asl];
#pragma unroll
    for (int ni = 0; ni < 4; ni++)
      bfr[ni] = *(const bf16x8*)&Bb[s][(wc * 64 + ni * 16 + fr) * 32 + asl];
    if (t + 2 < nt) STAGE_A(t + 2, sn);
    __builtin_amdgcn_s_barrier();
    asm volatile("s_waitcnt lgkmcnt(0)" ::: "memory");
    __builtin_amdgcn_sched_barrier(0);
    __builtin_amdgcn_s_setprio(1);
#pragma unroll
    for (int mi = 0; mi < 4; mi++)
#pragma unroll
      for (int ni = 0; ni < 4; ni++)
        acc[mi][ni] =
            __builtin_amdgcn_mfma_f32_16x16x32_bf16(af[mi], bfr[ni], acc[mi][ni], 0, 0, 0);
    __builtin_amdgcn_s_setprio(0);
    __builtin_amdgcn_s_barrier();
    // ---- phase 2 (vmcnt wait after MFMA cluster) ----
    bf16x8 af2[4];
#pragma unroll
    for (int mi = 0; mi < 4; mi++)
      af2[mi] = *(const bf16x8*)&Ab[s][(wr * 128 + (mi + 4) * 16 + fr) * 32 + asl];
    if (t + 2 < nt) STAGE_B(t + 2, sn);
    __builtin_amdgcn_s_barrier();
    asm volatile("s_waitcnt lgkmcnt(0)" ::: "memory");
    __builtin_amdgcn_sched_barrier(0);
    __builtin_amdgcn_s_setprio(1);
#pragma unroll
    for (int mi = 0; mi < 4; mi++)
#pragma unroll
      for (int ni = 0; ni < 4; ni++)
        acc[mi + 4][ni] =
            __builtin_amdgcn_mfma_f32_16x16x32_bf16(af2[mi], bfr[ni], acc[mi + 4][ni], 0, 0, 0);
    __builtin_amdgcn_s_setprio(0);
    if (t + 2 < nt) {
      asm volatile("s_waitcnt vmcnt(4)" ::: "memory");
    } else {
      asm volatile("s_waitcnt vmcnt(0)" ::: "memory");
    }
    __builtin_amdgcn_s_barrier();
  }
#undef STAGE_A
#undef STAGE_B

  // epilogue
#pragma unroll
  for (int mi = 0; mi < 8; mi++) {
    const int row = m0 + wr * 128 + mi * 16 + fg * 4;
#pragma unroll
    for (int ni = 0; ni < 4; ni++) {
      const int col = n0 + wc * 64 + ni * 16 + fr;
#pragma unroll
      for (int j = 0; j < 4; j++) {
        float v = acc[mi][ni][j];
        const int r = row + j;
        if constexpr (EPI == G_QG) {
          float vp = __shfl_xor(v, 1, 64);
          if (n0 < 2048) {
            int pos = posids[r];
            int d = col & 127;
            float c = cosT[pos * 128 + d], sn2 = sinT[pos * 128 + d];
            float o = (col & 1) ? (v * c + vp * sn2) : (v * c - vp * sn2);
            outQ[(size_t)r * 2048 + col] = (__bf16)(o * oscale);
          } else {
            float xx = v + bias[col - 2048];
            outG[(size_t)r * 2048 + (col - 2048)] = (__bf16)(1.0f / (1.0f + expf(-xx)));
          }
        } else if constexpr (EPI == G_RES) {
          outF[(size_t)r * N + col] = v + residual[(size_t)r * N + col];
        } else if constexpr (EPI == G_SILU) {
          outB[(size_t)r * N + col] = (__bf16)(v / (1.0f + expf(-v)));
        } else {
          outB[(size_t)(kz * MM + r) * N + col] = (__bf16)v;
        }
      }
    }
  }
}

// ---------------- combine: out = part0 + part1 + res (f32) ----------------
__global__ __launch_bounds__(256) void combine_k(const __bf16* __restrict__ parts,
                                                 const float* __restrict__ res,
                                                 float* __restrict__ out) {
  size_t i = ((size_t)blockIdx.x * 256 + threadIdx.x) * 8;
  bf16x8 p0 = *(const bf16x8*)&parts[i];
  bf16x8 p1 = *(const bf16x8*)&parts[(size_t)MM * 2048 + i];
  float4 a = *(const float4*)&res[i];
  float4 b = *(const float4*)&res[i + 4];
  float4 o0, o1;
  o0.x = (float)p0[0] + (float)p1[0] + a.x;
  o0.y = (float)p0[1] + (float)p1[1] + a.y;
  o0.z = (float)p0[2] + (float)p1[2] + a.z;
  o0.w = (float)p0[3] + (float)p1[3] + a.w;
  o1.x = (float)p0[4] + (float)p1[4] + b.x;
  o1.y = (float)p0[5] + (float)p1[5] + b.y;
  o1.z = (float)p0[6] + (float)p1[6] + b.z;
  o1.w = (float)p0[7] + (float)p1[7] + b.w;
  *(float4*)&out[i] = o0;
  *(float4*)&out[i + 4] = o1;
}

// ---------------- fused combine + RMSNorm ----------------
__global__ __launch_bounds__(256) void combine_rms_k(const __bf16* __restrict__ parts,
                                                     const float* __restrict__ res,
                                                     const float* __restrict__ w,
                                                     float* __restrict__ h1,
                                                     __bf16* __restrict__ h2) {
  const int row = blockIdx.x;
  const int t = threadIdx.x;
  const size_t i = (size_t)row * 2048 + t * 8;
  bf16x8 p0 = *(const bf16x8*)&parts[i];
  bf16x8 p1 = *(const bf16x8*)&parts[(size_t)MM * 2048 + i];
  float4 a = *(const float4*)&res[i];
  float4 b = *(const float4*)&res[i + 4];
  float v[8];
  v[0] = (float)p0[0] + (float)p1[0] + a.x;
  v[1] = (float)p0[1] + (float)p1[1] + a.y;
  v[2] = (float)p0[2] + (float)p1[2] + a.z;
  v[3] = (float)p0[3] + (float)p1[3] + a.w;
  v[4] = (float)p0[4] + (float)p1[4] + b.x;
  v[5] = (float)p0[5] + (float)p1[5] + b.y;
  v[6] = (float)p0[6] + (float)p1[6] + b.z;
  v[7] = (float)p0[7] + (float)p1[7] + b.w;
  float4 o0 = {v[0], v[1], v[2], v[3]};
  float4 o1 = {v[4], v[5], v[6], v[7]};
  *(float4*)&h1[i] = o0;
  *(float4*)&h1[i + 4] = o1;
  float ss = 0.f;
#pragma unroll
  for (int k = 0; k < 8; k++) ss += v[k] * v[k];
#pragma unroll
  for (int off = 32; off; off >>= 1) ss += __shfl_xor(ss, off, 64);
  __shared__ float red[4];
  if ((t & 63) == 0) red[t >> 6] = ss;
  __syncthreads();
  float tot = red[0] + red[1] + red[2] + red[3];
  float rs = rsqrtf(tot * (1.0f / DD) + 1e-6f);
  const float4 w1 = ((const float4*)w)[2 * t];
  const float4 w2 = ((const float4*)w)[2 * t + 1];
  bf16x8 ov;
  ov[0] = (__bf16)(v[0] * rs * w1.x);
  ov[1] = (__bf16)(v[1] * rs * w1.y);
  ov[2] = (__bf16)(v[2] * rs * w1.z);
  ov[3] = (__bf16)(v[3] * rs * w1.w);
  ov[4] = (__bf16)(v[4] * rs * w2.x);
  ov[5] = (__bf16)(v[5] * rs * w2.y);
  ov[6] = (__bf16)(v[6] * rs * w2.z);
  ov[7] = (__bf16)(v[7] * rs * w2.w);
  *(bf16x8*)(h2 + i) = ov;
}

// ---------------- K+V fused projection (128x128 tile) ----------------
__global__ __launch_bounds__(256) void gemm_kv_k(
    const __bf16* __restrict__ A, const __bf16* __restrict__ Bt,
    __bf16* __restrict__ kOut, __bf16* __restrict__ vOut,
    const float* __restrict__ cosT, const float* __restrict__ sinT,
    const int* __restrict__ posids, int K) {
  __shared__ __align__(16) __bf16 As[128 * 32];
  __shared__ __align__(16) __bf16 Bs[128 * 32];
  const int tid = threadIdx.x;
  const int lane = tid & 63;
  const int w = tid >> 6;
  const int wm = w >> 1, wn = w & 1;

  const int nwg = gridDim.x * gridDim.y;
  int wg = xcd_swizzle(blockIdx.y * gridDim.x + blockIdx.x, nwg);
  const int bx = wg % gridDim.x, by = wg / gridDim.x;
  const int m0 = by * 128;
  const int n0 = bx * 128;

  const int lr = lane >> 2;
  const int lc = (lane & 3) * 8;
  const __bf16* aSrc = A + (size_t)(m0 + 32 * w + lr) * K + lc;
  const __bf16* bSrc = Bt + (size_t)(n0 + 32 * w + lr) * K + lc;
  __bf16* aDst = &As[w * 1024];
  __bf16* bDst = &Bs[w * 1024];

  f32x4 acc[4][4];
#pragma unroll
  for (int i = 0; i < 4; i++)
#pragma unroll
    for (int j = 0; j < 4; j++) acc[i][j] = (f32x4){0.f, 0.f, 0.f, 0.f};

  const int fr = lane & 15;
  const int fc = (lane >> 4) * 8;

  for (int k0 = 0; k0 < K; k0 += 32) {
    __syncthreads();
    gload_lds16(aSrc + k0, aDst);
    gload_lds16(aSrc + k0 + (size_t)16 * K, aDst + 512);
    gload_lds16(bSrc + k0, bDst);
    gload_lds16(bSrc + k0 + (size_t)16 * K, bDst + 512);
    asm volatile("s_waitcnt vmcnt(0)" ::: "memory");
    __syncthreads();

    bf16x8 af[4], bfg[4];
#pragma unroll
    for (int i = 0; i < 4; i++)
      af[i] = *(const bf16x8*)&As[(wm * 64 + i * 16 + fr) * 32 + fc];
#pragma unroll
    for (int i = 0; i < 4; i++)
      bfg[i] = *(const bf16x8*)&Bs[(wn * 64 + i * 16 + fr) * 32 + fc];
#pragma unroll
    for (int mi = 0; mi < 4; mi++)
#pragma unroll
      for (int ni = 0; ni < 4; ni++)
        acc[mi][ni] =
            __builtin_amdgcn_mfma_f32_16x16x32_bf16(af[mi], bfg[ni], acc[mi][ni], 0, 0, 0);
  }

  const int fg = lane >> 4;
#pragma unroll
  for (int mi = 0; mi < 4; mi++) {
#pragma unroll
    for (int ni = 0; ni < 4; ni++) {
#pragma unroll
      for (int j = 0; j < 4; j++) {
        int row = m0 + wm * 64 + mi * 16 + fg * 4 + j;
        int col = n0 + wn * 64 + ni * 16 + fr;
        float v = acc[mi][ni][j];
        float vp = __shfl_xor(v, 1, 64);
        if (col < 512) {  // k: rope
          int pos = posids[row];
          int d = col & 127;
          float c = cosT[pos * 128 + d];
          float s = sinT[pos * 128 + d];
          float o = (col & 1) ? (v * c + vp * s) : (v * c - vp * s);
          kOut[(size_t)row * 512 + col] = (__bf16)o;
        } else {  // v: plain
          vOut[(size_t)row * 512 + (col - 512)] = (__bf16)v;
        }
      }
    }
  }
}

// ---------------- Flash attention (verified; heavy-first causal scheduling) ----------------
__global__ __launch_bounds__(256) void attn_k(const __bf16* __restrict__ Q,
                                              const __bf16* __restrict__ Kb,
                                              const __bf16* __restrict__ Vt,
                                              const __bf16* __restrict__ Gate,
                                              __bf16* __restrict__ Out) {
  __shared__ __align__(16) __bf16 Ks[2][64 * 128];
  __shared__ __align__(16) __bf16 Vs[2][128 * 64];
  __shared__ __align__(16) __bf16 Ps[4][16 * 64];
  const int tid = threadIdx.x;
  const int lane = tid & 63;
  const int w = tid >> 6;
  const int fr = lane & 15;
  const int fg = lane >> 4;

  const int nwg = gridDim.x * gridDim.y;
  int wg = xcd_swizzle(blockIdx.y * gridDim.x + blockIdx.x, nwg);
  // heavy-first: earliest-dispatched blocks in each XCD chunk get the LARGEST qb
  // (qb+1 KV-steps) so the causal critical path starts immediately (LPT packing).
  const int qb = (gridDim.x - 1) - (wg % gridDim.x);
  const int bh = wg / gridDim.x;
  const int q0 = qb * 64;
  const int b = bh >> 4, h = bh & 15;
  const int g = h >> 2;

  const size_t qrow = (size_t)(b * TT + q0 + w * 16 + fr);
  bf16x8 qf[4];
#pragma unroll
  for (int kt = 0; kt < 4; kt++)
    qf[kt] = *(const bf16x8*)&Q[qrow * 2048 + h * 128 + kt * 32 + fg * 8];

  const __bf16* kPtr[4];
  const __bf16* vPtr[4];
#pragma unroll
  for (int i = 0; i < 4; i++) {
    int krow = w * 16 + i * 4 + (lane >> 4);
    int kcol8 = (lane & 15) ^ (krow & 15);
    kPtr[i] = Kb + (size_t)(b * TT + krow) * 512 + g * 128 + kcol8 * 8;
    int dloc = w * 32 + i * 8 + (lane >> 3);
    int kv8 = (lane & 7) ^ (dloc & 7);
    vPtr[i] = Vt + (size_t)(g * 128 + dloc) * (size_t)MM + b * TT + kv8 * 8;
  }

  f32x4 o[8];
#pragma unroll
  for (int i = 0; i < 8; i++) o[i] = (f32x4){0.f, 0.f, 0.f, 0.f};
  float mrow[4] = {-3e38f, -3e38f, -3e38f, -3e38f};
  float lrow[4] = {0.f, 0.f, 0.f, 0.f};

  const int nsteps = qb + 1;

#pragma unroll
  for (int i = 0; i < 4; i++) {
    gload_lds16(kPtr[i], &Ks[0][w * 2048 + i * 512]);
    gload_lds16(vPtr[i], &Vs[0][w * 2048 + i * 512]);
  }
  __syncthreads();

  for (int t = 0; t < nsteps; t++) {
    const int cur = t & 1;
    const int kb = t * 64;
    if (t + 1 < nsteps) {
      const int nb = kb + 64;
#pragma unroll
      for (int i = 0; i < 4; i++) {
        gload_lds16(kPtr[i] + (size_t)nb * 512, &Ks[cur ^ 1][w * 2048 + i * 512]);
        gload_lds16(vPtr[i] + nb, &Vs[cur ^ 1][w * 2048 + i * 512]);
      }
    }

    f32x4 s[4];
#pragma unroll
    for (int nc = 0; nc < 4; nc++) s[nc] = (f32x4){0.f, 0.f, 0.f, 0.f};
#pragma unroll
    for (int nc = 0; nc < 4; nc++)
#pragma unroll
      for (int kt = 0; kt < 4; kt++) {
        bf16x8 kf = *(const bf16x8*)&Ks[cur][(nc * 16 + fr) * 128 + (((kt * 4 + fg) ^ fr) << 3)];
        s[nc] = __builtin_amdgcn_mfma_f32_16x16x32_bf16(qf[kt], kf, s[nc], 0, 0, 0);
      }

    float alpha[4];
#pragma unroll
    for (int j = 0; j < 4; j++) {
      const int qr = q0 + w * 16 + fg * 4 + j;
      float pv[4];
#pragma unroll
      for (int nc = 0; nc < 4; nc++) {
        int kc = kb + nc * 16 + fr;
        float val = s[nc][j];
        if (kc > qr) val = -1e9f;
        pv[nc] = val;
      }
      float tmx = fmaxf(fmaxf(pv[0], pv[1]), fmaxf(pv[2], pv[3]));
      tmx = fmaxf(tmx, __shfl_xor(tmx, 1, 64));
      tmx = fmaxf(tmx, __shfl_xor(tmx, 2, 64));
      tmx = fmaxf(tmx, __shfl_xor(tmx, 4, 64));
      tmx = fmaxf(tmx, __shfl_xor(tmx, 8, 64));
      float mnew = fmaxf(mrow[j], tmx);
      alpha[j] = __expf(mrow[j] - mnew);
      mrow[j] = mnew;
      float rsum = 0.f;
      const int q = fg * 4 + j;
#pragma unroll
      for (int nc = 0; nc < 4; nc++) {
        float e = __expf(pv[nc] - mnew);
        rsum += e;
        Ps[w][q * 64 + (((nc * 2 + (fr >> 3)) ^ (q & 7)) << 3) + (fr & 7)] = (__bf16)e;
      }
      rsum += __shfl_xor(rsum, 1, 64);
      rsum += __shfl_xor(rsum, 2, 64);
      rsum += __shfl_xor(rsum, 4, 64);
      rsum += __shfl_xor(rsum, 8, 64);
      lrow[j] = lrow[j] * alpha[j] + rsum;
    }
#pragma unroll
    for (int nd = 0; nd < 8; nd++)
#pragma unroll
      for (int j = 0; j < 4; j++) o[nd][j] *= alpha[j];

    bf16x8 pa[2];
#pragma unroll
    for (int sl = 0; sl < 2; sl++)
      pa[sl] = *(const bf16x8*)&Ps[w][fr * 64 + (((sl * 4 + fg) ^ (fr & 7)) << 3)];
#pragma unroll
    for (int nd = 0; nd < 8; nd++)
#pragma unroll
      for (int sl = 0; sl < 2; sl++) {
        bf16x8 vf =
            *(const bf16x8*)&Vs[cur][(nd * 16 + fr) * 64 + (((sl * 4 + fg) ^ (fr & 7)) << 3)];
        o[nd] = __builtin_amdgcn_mfma_f32_16x16x32_bf16(pa[sl], vf, o[nd], 0, 0, 0);
      }
    __syncthreads();
  }

  float invl[4];
#pragma unroll
  for (int j = 0; j < 4; j++) invl[j] = 1.0f / lrow[j];
#pragma unroll
  for (int nd = 0; nd < 8; nd++) {
#pragma unroll
    for (int j = 0; j < 4; j++) {
      int row = q0 + w * 16 + fg * 4 + j;
      int d = nd * 16 + fr;
      size_t idx = (size_t)(b * TT + row) * 2048 + h * 128 + d;
      float val = o[nd][j] * invl[j] * (float)Gate[idx];
      Out[idx] = (__bf16)val;
    }
  }
}

// ---------------- host ----------------
extern "C" void kernel_launch(void* const* d_in, const int* in_sizes, int n_in,
                              void* d_out, int out_size, void* d_ws, size_t ws_size,
                              hipStream_t stream) {
  const float* hidden = (const float*)d_in[0];
  const int* posids = (const int*)d_in[2];
  const float* attn_w = (const float*)d_in[3];
  const float* mlp_w = (const float*)d_in[4];
  const float* wq = (const float*)d_in[5];
  const float* wk = (const float*)d_in[6];
  const float* wv = (const float*)d_in[7];
  const float* wo = (const float*)d_in[8];
  const float* gw = (const float*)d_in[9];
  const float* gb = (const float*)d_in[10];
  const float* f1 = (const float*)d_in[11];
  const float* f2 = (const float*)d_in[12];

  char* p = (char*)d_ws;
  auto alloc = [&](size_t n) {
    char* r = p;
    p += (n + 255) & ~(size_t)255;
    return r;
  };
  __bf16* wqg_t = (__bf16*)alloc((size_t)4096 * 2048 * 2);
  __bf16* wkv_t = (__bf16*)alloc((size_t)1024 * 2048 * 2);
  __bf16* wo_t = (__bf16*)alloc((size_t)2048 * 2048 * 2);
  __bf16* f1_t = (__bf16*)alloc((size_t)NI * 2048 * 2);  // reused as fc2 partials
  __bf16* f2_t = (__bf16*)alloc((size_t)2048 * NI * 2);
  __bf16* h_bf = (__bf16*)alloc((size_t)MM * DD * 2);
  float* h1 = (float*)alloc((size_t)MM * 2048 * 4);

  char* regionA = alloc((size_t)64 * 1024 * 1024);
  __bf16* q_bf = (__bf16*)(regionA);
  __bf16* gate_bf = (__bf16*)(regionA + (size_t)16 * 1024 * 1024);
  __bf16* attn_g = (__bf16*)(regionA + (size_t)32 * 1024 * 1024);
  __bf16* k_bf = (__bf16*)(regionA + (size_t)48 * 1024 * 1024);
  __bf16* v_bf = (__bf16*)(regionA + (size_t)52 * 1024 * 1024);
  __bf16* v_t = (__bf16*)(regionA + (size_t)56 * 1024 * 1024);
  float* cosT = (float*)(regionA + (size_t)60 * 1024 * 1024);
  float* sinT = (float*)(regionA + (size_t)62 * 1024 * 1024);
  __bf16* mlp1 = (__bf16*)(regionA);
  __bf16* parts_wo = (__bf16*)(regionA);  // 32 MiB; q_bf/gate_bf dead after attn
  __bf16* parts_fc2 = (__bf16*)f1_t;      // 32 MiB; f1_t dead after fc1

  rope_tables_k<<<4096, 128, 0, stream>>>(cosT, sinT);

  transpose_to_bf16_k<float><<<dim3(64, 64), 256, 0, stream>>>(wq, wqg_t, 2048, 2048);
  transpose_to_bf16_k<float><<<dim3(64, 64), 256, 0, stream>>>(gw, wqg_t + (size_t)2048 * 2048, 2048, 2048);
  transpose_to_bf16_k<float><<<dim3(16, 64), 256, 0, stream>>>(wk, wkv_t, 2048, 512);
  transpose_to_bf16_k<float><<<dim3(16, 64), 256, 0, stream>>>(wv, wkv_t + (size_t)512 * 2048, 2048, 512);
  transpose_to_bf16_k<float><<<dim3(64, 64), 256, 0, stream>>>(wo, wo_t, 2048, 2048);
  transpose_to_bf16_k<float><<<dim3(256, 64), 256, 0, stream>>>(f1, f1_t, 2048, NI);
  transpose_to_bf16_k<float><<<dim3(64, 256), 256, 0, stream>>>(f2, f2_t, NI, 2048);

  rmsnorm_k<<<MM, 256, 0, stream>>>(hidden, attn_w, h_bf);

  const float qsc = 0.08838834764831845f;  // 1/sqrt(128)
  // fused q+gate
  gemm256_k<G_QG><<<dim3(16, 16), 512, 0, stream>>>(
      h_bf, wqg_t, nullptr, nullptr, q_bf, gate_bf, gb, nullptr, cosT, sinT, posids,
      4096, 2048, 2048, qsc);
  // fused k+v
  gemm_kv_k<<<dim3(8, 32), 256, 0, stream>>>(h_bf, wkv_t, k_bf, v_bf, cosT, sinT, posids, 2048);

  transpose_to_bf16_k<__bf16><<<dim3(16, 128), 256, 0, stream>>>(v_bf, v_t, MM, 512);

  attn_k<<<dim3(32, 32), 256, 0, stream>>>(q_bf, k_bf, v_t, gate_bf, attn_g);

  // wo split-K (z=2) -> bf16 partials, then fused combine + mlp-RMSNorm
  gemm256_k<G_PART><<<dim3(8, 16, 2), 512, 0, stream>>>(
      attn_g, wo_t, parts_wo, nullptr, nullptr, nullptr, nullptr, nullptr, nullptr, nullptr,
      nullptr, 2048, 1024, 2048, 1.0f);
  combine_rms_k<<<MM, 256, 0, stream>>>(parts_wo, hidden, mlp_w, h1, h_bf);

  // fc1 + SiLU
  gemm256_k<G_SILU><<<dim3(32, 16), 512, 0, stream>>>(
      h_bf, f1_t, mlp1, nullptr, nullptr, nullptr, nullptr, nullptr, nullptr, nullptr, nullptr,
      NI, 2048, 2048, 1.0f);

  // fc2 split-K (z=2) -> bf16 partials
  gemm256_k<G_PART><<<dim3(8, 16, 2), 512, 0, stream>>>(
      mlp1, f2_t, parts_fc2, nullptr, nullptr, nullptr, nullptr, nullptr, nullptr, nullptr,
      nullptr, 2048, 4096, NI, 1.0f);

  // d_out = part0 + part1 + h1
  combine_k<<<4096, 256, 0, stream>>>(parts_fc2, h1, (float*)d_out);
}